// Round 7
// baseline (379.988 us; speedup 1.0000x reference)
//
#include <hip/hip_runtime.h>
#include <hip/hip_bf16.h>

#define IN_CH 128
#define HID 64
#define OUT_CH 16

#define G_SH 7
#define G_SZ 128          // dst nodes per bucket
#define NBK_MAX 800       // max buckets (n <= 102400)
#define CHUNK 4096        // edges per bucketing block
#define SORT_CAP 4096     // max edges per bucket (mean 2048, std ~45)

// ---------------- degree ----------------

__global__ void k_zero_int(int* __restrict__ p, int n) {
    int i = blockIdx.x * blockDim.x + threadIdx.x;
    if (i < n) p[i] = 0;
}

__global__ void k_count(const int* __restrict__ ei, int* __restrict__ counts, int E) {
    int e = blockIdx.x * blockDim.x + threadIdx.x;
    if (e < E) atomicAdd(&counts[ei[E + e]], 1);  // row 1 = dst
}

// phase 1: per-block exclusive scan counts -> rowptr (counts preserved) + fused dinv
__global__ __launch_bounds__(256) void k_scan_local(const int* __restrict__ counts,
                                                    int* __restrict__ rowptr,
                                                    int* __restrict__ blk_sum,
                                                    float* __restrict__ dinv, int n) {
    __shared__ int s[256];
    int i = blockIdx.x * 256 + threadIdx.x;
    int v = (i < n) ? counts[i] : 0;
    if (i < n) dinv[i] = rsqrtf((float)(v + 1));  // +1 = self-loop
    s[threadIdx.x] = v;
    __syncthreads();
    for (int off = 1; off < 256; off <<= 1) {
        int t = (threadIdx.x >= off) ? s[threadIdx.x - off] : 0;
        __syncthreads();
        s[threadIdx.x] += t;
        __syncthreads();
    }
    if (i < n) rowptr[i] = s[threadIdx.x] - v;  // exclusive within block
    if (threadIdx.x == 255) blk_sum[blockIdx.x] = s[255];
}

// phase 2: single-block exclusive scan of block sums
__global__ __launch_bounds__(256) void k_scan_blocks(int* __restrict__ blk, int nblk) {
    __shared__ int s[256];
    __shared__ int sh_carry;
    if (threadIdx.x == 0) sh_carry = 0;
    __syncthreads();
    for (int base = 0; base < nblk; base += 256) {
        int carry = sh_carry;
        int i = base + threadIdx.x;
        int v = (i < nblk) ? blk[i] : 0;
        s[threadIdx.x] = v;
        __syncthreads();
        for (int off = 1; off < 256; off <<= 1) {
            int t = (threadIdx.x >= off) ? s[threadIdx.x - off] : 0;
            __syncthreads();
            s[threadIdx.x] += t;
            __syncthreads();
        }
        if (i < nblk) blk[i] = carry + s[threadIdx.x] - v;
        if (threadIdx.x == 255) sh_carry = carry + s[255];
        __syncthreads();
    }
}

// phase 3: add block offsets; init per-bucket cursor = rowptr[b<<7]
__global__ void k_scan_add(int* __restrict__ rowptr, const int* __restrict__ blk,
                           int* __restrict__ bcursor, int n) {
    int i = blockIdx.x * blockDim.x + threadIdx.x;
    if (i < n) {
        int r = rowptr[i] + blk[blockIdx.x];
        rowptr[i] = r;
        if ((i & (G_SZ - 1)) == 0) bcursor[i >> G_SH] = r;
    }
}

// ---------------- edge bucketing (coarse sort by dst>>7) ----------------
// packed word: (d_local << 17) | src   (src < 2^17)
__global__ __launch_bounds__(256) void k_bucket(const int* __restrict__ ei,
                                                int* __restrict__ bcursor,
                                                int* __restrict__ packed, int E, int nb) {
    __shared__ int hcnt[NBK_MAX];
    __shared__ int hoff[NBK_MAX];
    __shared__ int hbase[NBK_MAX];
    __shared__ int hcur[NBK_MAX];
    __shared__ int stage[CHUNK];
    __shared__ unsigned short sbk[CHUNK];
    __shared__ int scan_s[256];
    __shared__ int sh_carry;

    int tid = threadIdx.x;
    int base = blockIdx.x * CHUNK;
    int cnt = E - base;
    if (cnt > CHUNK) cnt = CHUNK;
    for (int t = tid; t < nb; t += 256) { hcnt[t] = 0; hcur[t] = 0; }
    if (tid == 0) sh_carry = 0;
    __syncthreads();

    int mp[CHUNK / 256], mb[CHUNK / 256];
#pragma unroll
    for (int k = 0; k < CHUNK / 256; ++k) {
        int idx = base + k * 256 + tid;
        int p = 0, b = -1;
        if (idx < E) {
            int s = ei[idx];
            int d = ei[E + idx];
            b = d >> G_SH;
            p = ((d & (G_SZ - 1)) << 17) | s;
            atomicAdd(&hcnt[b], 1);
        }
        mp[k] = p; mb[k] = b;
    }
    __syncthreads();

    // exclusive scan of hcnt -> hoff
    for (int s0 = 0; s0 < nb; s0 += 256) {
        int i = s0 + tid;
        int v = (i < nb) ? hcnt[i] : 0;
        scan_s[tid] = v;
        __syncthreads();
        for (int off = 1; off < 256; off <<= 1) {
            int t = (tid >= off) ? scan_s[tid - off] : 0;
            __syncthreads();
            scan_s[tid] += t;
            __syncthreads();
        }
        if (i < nb) hoff[i] = sh_carry + scan_s[tid] - v;
        __syncthreads();
        if (tid == 255) sh_carry += scan_s[255];
        __syncthreads();
    }

    // reserve global space per bucket
    for (int t = tid; t < nb; t += 256)
        if (hcnt[t] > 0) hbase[t] = atomicAdd(&bcursor[t], hcnt[t]);
    __syncthreads();

    // LDS scatter into bucket-ordered staging
#pragma unroll
    for (int k = 0; k < CHUNK / 256; ++k) {
        int b = mb[k];
        if (b >= 0) {
            int slot = hoff[b] + atomicAdd(&hcur[b], 1);
            stage[slot] = mp[k];
            sbk[slot] = (unsigned short)b;
        }
    }
    __syncthreads();

    // coalesced run write-out
    for (int i = tid; i < cnt; i += 256) {
        int b = sbk[i];
        packed[hbase[b] + (i - hoff[b])] = stage[i];
    }
}

// ---------------- per-bucket fine counting sort (in place, strips to src) -------

__global__ __launch_bounds__(256) void k_sortbkt(const int* __restrict__ rowptr,
                                                 const int* __restrict__ counts,
                                                 int* __restrict__ packed, int n) {
    __shared__ int sc[G_SZ];
    __shared__ int lcur[G_SZ];
    __shared__ int stage[SORT_CAP];
    __shared__ int sorted_[SORT_CAP];
    __shared__ int sh_L, sh_base;

    int tid = threadIdx.x;
    int d0 = blockIdx.x << G_SH;
    int v = 0;
    if (tid < G_SZ) {
        int d = d0 + tid;
        v = (d < n) ? counts[d] : 0;
        sc[tid] = v;
    }
    if (tid == 0) sh_base = rowptr[d0];
    __syncthreads();
    for (int off = 1; off < G_SZ; off <<= 1) {
        int t = (tid < G_SZ && tid >= off) ? sc[tid - off] : 0;
        __syncthreads();
        if (tid < G_SZ) sc[tid] += t;
        __syncthreads();
    }
    if (tid < G_SZ) lcur[tid] = sc[tid] - v;  // exclusive
    if (tid == G_SZ - 1) sh_L = sc[G_SZ - 1];
    __syncthreads();

    int L = sh_L, base = sh_base;
    for (int i = tid; i < L; i += 256) stage[i] = packed[base + i];
    __syncthreads();
    for (int i = tid; i < L; i += 256) {
        int p = stage[i];
        int dl = p >> 17;
        int pos = atomicAdd(&lcur[dl], 1);
        sorted_[pos] = p & 0x1FFFF;
    }
    __syncthreads();
    for (int i = tid; i < L; i += 256) packed[base + i] = sorted_[i];
}

// ---------------- layer 1 ----------------

// xlp = bf16(dinv * (x @ W1)); 16 nodes/block, 4 nodes/thread, W1 in LDS
__global__ __launch_bounds__(256) void k_gemm1(const float* __restrict__ x,
                                               const float* __restrict__ W,
                                               const float* __restrict__ dinv,
                                               __hip_bfloat16* __restrict__ xlp, int n) {
    __shared__ float sW[IN_CH * HID];  // 32 KB
    __shared__ float sx[16][IN_CH];    // 8 KB
    int tid = threadIdx.x;
    int node0 = blockIdx.x * 16;
    for (int i = tid; i < IN_CH * HID / 4; i += 256)
        ((float4*)sW)[i] = ((const float4*)W)[i];
    for (int i = tid; i < 16 * IN_CH / 4; i += 256) {
        int r = i >> 5, k4 = i & 31;
        int node = node0 + r;
        float4 v = (node < n) ? ((const float4*)(x + (size_t)node * IN_CH))[k4]
                              : make_float4(0.f, 0.f, 0.f, 0.f);
        ((float4*)sx[r])[k4] = v;
    }
    __syncthreads();
    int r = tid >> 6, j = tid & 63;  // wave -> node slot, lane -> channel
    float a0 = 0.f, a1 = 0.f, a2 = 0.f, a3 = 0.f;
    for (int k = 0; k < IN_CH; k += 4) {
        float4 xa = *(const float4*)&sx[r][k];
        float4 xb = *(const float4*)&sx[r + 4][k];
        float4 xc = *(const float4*)&sx[r + 8][k];
        float4 xd = *(const float4*)&sx[r + 12][k];
        float w0 = sW[k * HID + j], w1 = sW[(k + 1) * HID + j];
        float w2 = sW[(k + 2) * HID + j], w3 = sW[(k + 3) * HID + j];
        a0 += xa.x * w0 + xa.y * w1 + xa.z * w2 + xa.w * w3;
        a1 += xb.x * w0 + xb.y * w1 + xb.z * w2 + xb.w * w3;
        a2 += xc.x * w0 + xc.y * w1 + xc.z * w2 + xc.w * w3;
        a3 += xd.x * w0 + xd.y * w1 + xd.z * w2 + xd.w * w3;
    }
    int na = node0 + r, nb_ = node0 + r + 4, nc = node0 + r + 8, nd = node0 + r + 12;
    if (na < n) xlp[(size_t)na * HID + j] = __float2bfloat16(dinv[na] * a0);
    if (nb_ < n) xlp[(size_t)nb_ * HID + j] = __float2bfloat16(dinv[nb_] * a1);
    if (nc < n) xlp[(size_t)nc * HID + j] = __float2bfloat16(dinv[nc] * a2);
    if (nd < n) xlp[(size_t)nd * HID + j] = __float2bfloat16(dinv[nd] * a3);
}

// hout[d] = relu(dd*(sum_s xlp[s] + xlp[d]) + b1), bf16 gathers.
// One wave per dst; two 32-lane halves process alternating edges; 4-deep unroll/half.
__global__ __launch_bounds__(256) void k_agg1(const int* __restrict__ rowptr,
                                              const int* __restrict__ counts,
                                              const int* __restrict__ esrc,
                                              const float* __restrict__ dinv,
                                              const __hip_bfloat16* __restrict__ xlp,
                                              const float* __restrict__ b,
                                              float* __restrict__ hout, int n) {
    int d = blockIdx.x * 4 + (threadIdx.x >> 6);
    if (d >= n) return;
    int lane = threadIdx.x & 63;
    int hf = lane >> 5;      // half: 0 = even edges, 1 = odd edges
    int cl = lane & 31;      // channel pair -> ch {2cl, 2cl+1}
    int j0 = rowptr[d];
    int cnt = counts[d];
    float a0 = 0.f, a1 = 0.f;
    int t = 0;
    for (; t + 8 <= cnt; t += 8) {
        int base = j0 + t + hf;
        int s0 = esrc[base], s1 = esrc[base + 2], s2 = esrc[base + 4], s3 = esrc[base + 6];
        unsigned w0 = ((const unsigned*)(xlp + (size_t)s0 * HID))[cl];
        unsigned w1 = ((const unsigned*)(xlp + (size_t)s1 * HID))[cl];
        unsigned w2 = ((const unsigned*)(xlp + (size_t)s2 * HID))[cl];
        unsigned w3 = ((const unsigned*)(xlp + (size_t)s3 * HID))[cl];
        a0 += (__uint_as_float(w0 << 16) + __uint_as_float(w1 << 16)) +
              (__uint_as_float(w2 << 16) + __uint_as_float(w3 << 16));
        a1 += (__uint_as_float(w0 & 0xffff0000u) + __uint_as_float(w1 & 0xffff0000u)) +
              (__uint_as_float(w2 & 0xffff0000u) + __uint_as_float(w3 & 0xffff0000u));
    }
    for (; t < cnt; ++t) {
        if ((t & 1) == hf) {
            int s = esrc[j0 + t];
            unsigned w = ((const unsigned*)(xlp + (size_t)s * HID))[cl];
            a0 += __uint_as_float(w << 16);
            a1 += __uint_as_float(w & 0xffff0000u);
        }
    }
    // combine the two halves
    a0 += __shfl_xor(a0, 32);
    a1 += __shfl_xor(a1, 32);
    if (hf == 0) {
        unsigned ws = ((const unsigned*)(xlp + (size_t)d * HID))[cl];  // self-loop
        float dd = dinv[d];
        float v0 = dd * (a0 + __uint_as_float(ws << 16)) + b[2 * cl];
        float v1 = dd * (a1 + __uint_as_float(ws & 0xffff0000u)) + b[2 * cl + 1];
        ((float2*)(hout + (size_t)d * HID))[cl] = make_float2(fmaxf(v0, 0.f), fmaxf(v1, 0.f));
    }
}

// ---------------- layer 2 ----------------

// hlp = dinv * (h @ W2); 16 nodes/block (fp32 throughout)
__global__ __launch_bounds__(256) void k_gemm2(const float* __restrict__ h,
                                               const float* __restrict__ W,
                                               const float* __restrict__ dinv,
                                               float* __restrict__ hlp, int n) {
    __shared__ float sW[HID * OUT_CH];
    __shared__ float sh[16][HID];
    int tid = threadIdx.x;
    for (int t = tid; t < HID * OUT_CH; t += 256) sW[t] = W[t];
    int node0 = blockIdx.x * 16;
    for (int t = tid; t < 16 * HID / 4; t += 256) {
        int r = t >> 4, k4 = t & 15;
        int node = node0 + r;
        float4 v = (node < n) ? ((const float4*)(h + (size_t)node * HID))[k4]
                              : make_float4(0.f, 0.f, 0.f, 0.f);
        ((float4*)sh[r])[k4] = v;
    }
    __syncthreads();
    int r = tid >> 4, j = tid & 15;
    int node = node0 + r;
    if (node >= n) return;
    float acc = 0.f;
#pragma unroll
    for (int k = 0; k < HID; ++k)
        acc += sh[r][k] * sW[k * OUT_CH + j];
    hlp[(size_t)node * OUT_CH + j] = dinv[node] * acc;
}

// out[d] = dd * (sum_s hlp[s] + hlp[d]) + b2. One 16-lane group per dst; 4-edge unroll.
__global__ __launch_bounds__(256) void k_agg2(const int* __restrict__ rowptr,
                                              const int* __restrict__ counts,
                                              const int* __restrict__ esrc,
                                              const float* __restrict__ dinv,
                                              const float* __restrict__ hlp,
                                              const float* __restrict__ b,
                                              float* __restrict__ out, int n) {
    int d = blockIdx.x * 16 + (threadIdx.x >> 4);
    int c = threadIdx.x & 15;
    if (d >= n) return;
    int j0 = rowptr[d], j1 = j0 + counts[d];
    float acc = 0.f;
    int j = j0;
    for (; j + 4 <= j1; j += 4) {
        int s0 = esrc[j], s1 = esrc[j + 1], s2 = esrc[j + 2], s3 = esrc[j + 3];
        float v0 = hlp[(size_t)s0 * OUT_CH + c];
        float v1 = hlp[(size_t)s1 * OUT_CH + c];
        float v2 = hlp[(size_t)s2 * OUT_CH + c];
        float v3 = hlp[(size_t)s3 * OUT_CH + c];
        acc += (v0 + v1) + (v2 + v3);
    }
    for (; j < j1; ++j) acc += hlp[(size_t)esrc[j] * OUT_CH + c];
    float dd = dinv[d];
    out[(size_t)d * OUT_CH + c] = dd * (acc + hlp[(size_t)d * OUT_CH + c]) + b[c];
}

extern "C" void kernel_launch(void* const* d_in, const int* in_sizes, int n_in,
                              void* d_out, int out_size, void* d_ws, size_t ws_size,
                              hipStream_t stream) {
    const float* x  = (const float*)d_in[0];
    const int* ei   = (const int*)d_in[1];   // int32 from harness
    const float* W1 = (const float*)d_in[2];
    const float* b1 = (const float*)d_in[3];
    const float* W2 = (const float*)d_in[4];
    const float* b2 = (const float*)d_in[5];
    float* out = (float*)d_out;

    const int n = in_sizes[0] / IN_CH;      // 100000
    const int E = in_sizes[1] / 2;          // 1600000
    const int nblk = (n + 255) / 256;       // 391
    const int nb = (n + G_SZ - 1) >> G_SH;  // 782 buckets

    // workspace (ints): counts n | rowptr n | blk 512 | bcursor 1024 | packed E |
    //   dinv n | xlp 32n (bf16 64/node, aliased by hlp f32 16/node) | hout 64n
    //   total = 99n + E + 1536 ints ~= 46 MB
    int* counts  = (int*)d_ws;
    int* rowptr  = counts + n;
    int* blk     = rowptr + n;
    int* bcursor = blk + 512;
    int* packed  = bcursor + 1024;
    float* dinv  = (float*)(packed + E);
    __hip_bfloat16* xlp = (__hip_bfloat16*)(dinv + n);  // n*64 bf16
    float* hlp   = (float*)xlp;                          // alias: xlp dead after k_agg1
    float* hout  = (float*)(xlp + (size_t)n * HID);      // n*64 f32

    // degree + rowptr + dinv + bucket cursors
    k_zero_int<<<nblk, 256, 0, stream>>>(counts, n);
    k_count<<<(E + 255) / 256, 256, 0, stream>>>(ei, counts, E);
    k_scan_local<<<nblk, 256, 0, stream>>>(counts, rowptr, blk, dinv, n);
    k_scan_blocks<<<1, 256, 0, stream>>>(blk, nblk);
    k_scan_add<<<nblk, 256, 0, stream>>>(rowptr, blk, bcursor, n);

    // coarse bucket sort + per-bucket fine sort (in place -> CSR-ordered src ids)
    k_bucket<<<(E + CHUNK - 1) / CHUNK, 256, 0, stream>>>(ei, bcursor, packed, E, nb);
    k_sortbkt<<<nb, 256, 0, stream>>>(rowptr, counts, packed, n);

    // layer 1
    k_gemm1<<<(n + 15) / 16, 256, 0, stream>>>(x, W1, dinv, xlp, n);
    k_agg1<<<(n + 3) / 4, 256, 0, stream>>>(rowptr, counts, packed, dinv, xlp, b1, hout, n);

    // layer 2
    k_gemm2<<<(n + 15) / 16, 256, 0, stream>>>(hout, W2, dinv, hlp, n);
    k_agg2<<<(n + 15) / 16, 256, 0, stream>>>(rowptr, counts, packed, dinv, hlp, b2, out, n);
}

// Round 8
// 281.513 us; speedup vs baseline: 1.3498x; 1.3498x over previous
//
#include <hip/hip_runtime.h>
#include <hip/hip_bf16.h>

#define IN_CH 128
#define HID 64
#define OUT_CH 16

#define G_SH 7
#define G_SZ 128          // dst nodes per bucket
#define NBK_MAX 800       // max buckets (n <= 102400)
#define CHUNK 4096        // edges per bucketing block
#define SORT_CAP 4096     // max edges per bucket (mean 2048, std ~45)

// ---------------- degree ----------------

__global__ void k_zero_int(int* __restrict__ p, int n) {
    int i = blockIdx.x * blockDim.x + threadIdx.x;
    if (i < n) p[i] = 0;
}

__global__ void k_count(const int* __restrict__ ei, int* __restrict__ counts, int E) {
    int e = blockIdx.x * blockDim.x + threadIdx.x;
    if (e < E) atomicAdd(&counts[ei[E + e]], 1);  // row 1 = dst
}

// phase 1: per-block exclusive scan counts -> rowptr (counts preserved) + fused dinv
__global__ __launch_bounds__(256) void k_scan_local(const int* __restrict__ counts,
                                                    int* __restrict__ rowptr,
                                                    int* __restrict__ blk_sum,
                                                    float* __restrict__ dinv, int n) {
    __shared__ int s[256];
    int i = blockIdx.x * 256 + threadIdx.x;
    int v = (i < n) ? counts[i] : 0;
    if (i < n) dinv[i] = rsqrtf((float)(v + 1));  // +1 = self-loop
    s[threadIdx.x] = v;
    __syncthreads();
    for (int off = 1; off < 256; off <<= 1) {
        int t = (threadIdx.x >= off) ? s[threadIdx.x - off] : 0;
        __syncthreads();
        s[threadIdx.x] += t;
        __syncthreads();
    }
    if (i < n) rowptr[i] = s[threadIdx.x] - v;  // exclusive within block
    if (threadIdx.x == 255) blk_sum[blockIdx.x] = s[255];
}

// phase 2: single-block exclusive scan of block sums
__global__ __launch_bounds__(256) void k_scan_blocks(int* __restrict__ blk, int nblk) {
    __shared__ int s[256];
    __shared__ int sh_carry;
    if (threadIdx.x == 0) sh_carry = 0;
    __syncthreads();
    for (int base = 0; base < nblk; base += 256) {
        int carry = sh_carry;
        int i = base + threadIdx.x;
        int v = (i < nblk) ? blk[i] : 0;
        s[threadIdx.x] = v;
        __syncthreads();
        for (int off = 1; off < 256; off <<= 1) {
            int t = (threadIdx.x >= off) ? s[threadIdx.x - off] : 0;
            __syncthreads();
            s[threadIdx.x] += t;
            __syncthreads();
        }
        if (i < nblk) blk[i] = carry + s[threadIdx.x] - v;
        if (threadIdx.x == 255) sh_carry = carry + s[255];
        __syncthreads();
    }
}

// phase 3: add block offsets; init per-bucket cursor = rowptr[b<<7]
__global__ void k_scan_add(int* __restrict__ rowptr, const int* __restrict__ blk,
                           int* __restrict__ bcursor, int n) {
    int i = blockIdx.x * blockDim.x + threadIdx.x;
    if (i < n) {
        int r = rowptr[i] + blk[blockIdx.x];
        rowptr[i] = r;
        if ((i & (G_SZ - 1)) == 0) bcursor[i >> G_SH] = r;
    }
}

// ---------------- edge bucketing (coarse sort by dst>>7) ----------------
// packed word: (d_local << 17) | src   (src < 2^17)
__global__ __launch_bounds__(256) void k_bucket(const int* __restrict__ ei,
                                                int* __restrict__ bcursor,
                                                int* __restrict__ packed, int E, int nb) {
    __shared__ int hcnt[NBK_MAX];
    __shared__ int hoff[NBK_MAX];
    __shared__ int hbase[NBK_MAX];
    __shared__ int hcur[NBK_MAX];
    __shared__ int stage[CHUNK];
    __shared__ unsigned short sbk[CHUNK];
    __shared__ int scan_s[256];
    __shared__ int sh_carry;

    int tid = threadIdx.x;
    int base = blockIdx.x * CHUNK;
    int cnt = E - base;
    if (cnt > CHUNK) cnt = CHUNK;
    for (int t = tid; t < nb; t += 256) { hcnt[t] = 0; hcur[t] = 0; }
    if (tid == 0) sh_carry = 0;
    __syncthreads();

    int mp[CHUNK / 256], mb[CHUNK / 256];
#pragma unroll
    for (int k = 0; k < CHUNK / 256; ++k) {
        int idx = base + k * 256 + tid;
        int p = 0, b = -1;
        if (idx < E) {
            int s = ei[idx];
            int d = ei[E + idx];
            b = d >> G_SH;
            p = ((d & (G_SZ - 1)) << 17) | s;
            atomicAdd(&hcnt[b], 1);
        }
        mp[k] = p; mb[k] = b;
    }
    __syncthreads();

    // exclusive scan of hcnt -> hoff
    for (int s0 = 0; s0 < nb; s0 += 256) {
        int i = s0 + tid;
        int v = (i < nb) ? hcnt[i] : 0;
        scan_s[tid] = v;
        __syncthreads();
        for (int off = 1; off < 256; off <<= 1) {
            int t = (tid >= off) ? scan_s[tid - off] : 0;
            __syncthreads();
            scan_s[tid] += t;
            __syncthreads();
        }
        if (i < nb) hoff[i] = sh_carry + scan_s[tid] - v;
        __syncthreads();
        if (tid == 255) sh_carry += scan_s[255];
        __syncthreads();
    }

    // reserve global space per bucket
    for (int t = tid; t < nb; t += 256)
        if (hcnt[t] > 0) hbase[t] = atomicAdd(&bcursor[t], hcnt[t]);
    __syncthreads();

    // LDS scatter into bucket-ordered staging
#pragma unroll
    for (int k = 0; k < CHUNK / 256; ++k) {
        int b = mb[k];
        if (b >= 0) {
            int slot = hoff[b] + atomicAdd(&hcur[b], 1);
            stage[slot] = mp[k];
            sbk[slot] = (unsigned short)b;
        }
    }
    __syncthreads();

    // coalesced run write-out
    for (int i = tid; i < cnt; i += 256) {
        int b = sbk[i];
        packed[hbase[b] + (i - hoff[b])] = stage[i];
    }
}

// ---------------- per-bucket fine counting sort (in place, strips to src) -------

__global__ __launch_bounds__(256) void k_sortbkt(const int* __restrict__ rowptr,
                                                 const int* __restrict__ counts,
                                                 int* __restrict__ packed, int n) {
    __shared__ int sc[G_SZ];
    __shared__ int lcur[G_SZ];
    __shared__ int stage[SORT_CAP];
    __shared__ int sorted_[SORT_CAP];
    __shared__ int sh_L, sh_base;

    int tid = threadIdx.x;
    int d0 = blockIdx.x << G_SH;
    int v = 0;
    if (tid < G_SZ) {
        int d = d0 + tid;
        v = (d < n) ? counts[d] : 0;
        sc[tid] = v;
    }
    if (tid == 0) sh_base = rowptr[d0];
    __syncthreads();
    for (int off = 1; off < G_SZ; off <<= 1) {
        int t = (tid < G_SZ && tid >= off) ? sc[tid - off] : 0;
        __syncthreads();
        if (tid < G_SZ) sc[tid] += t;
        __syncthreads();
    }
    if (tid < G_SZ) lcur[tid] = sc[tid] - v;  // exclusive
    if (tid == G_SZ - 1) sh_L = sc[G_SZ - 1];
    __syncthreads();

    int L = sh_L, base = sh_base;
    for (int i = tid; i < L; i += 256) stage[i] = packed[base + i];
    __syncthreads();
    for (int i = tid; i < L; i += 256) {
        int p = stage[i];
        int dl = p >> 17;
        int pos = atomicAdd(&lcur[dl], 1);
        sorted_[pos] = p & 0x1FFFF;
    }
    __syncthreads();
    for (int i = tid; i < L; i += 256) packed[base + i] = sorted_[i];
}

// ---------------- layer 1 ----------------

// xlp = bf16(dinv * (x @ W1)); 8 nodes/block, 2 nodes/thread (round-6 proven shape)
__global__ __launch_bounds__(256) void k_gemm1(const float* __restrict__ x,
                                               const float* __restrict__ W,
                                               const float* __restrict__ dinv,
                                               __hip_bfloat16* __restrict__ xlp, int n) {
    __shared__ float sx[8][IN_CH];
    int node0 = blockIdx.x * 8;
    int tid = threadIdx.x;
    {
        int r = tid >> 5, k4 = tid & 31;
        int node = node0 + r;
        float4 v = (node < n) ? ((const float4*)(x + (size_t)node * IN_CH))[k4]
                              : make_float4(0.f, 0.f, 0.f, 0.f);
        ((float4*)sx[r])[k4] = v;
    }
    __syncthreads();
    int r = tid >> 6, j = tid & 63;
    float acc0 = 0.f, acc1 = 0.f;
#pragma unroll 8
    for (int k = 0; k < IN_CH; ++k) {
        float w = W[k * HID + j];
        acc0 += sx[r][k] * w;
        acc1 += sx[r + 4][k] * w;
    }
    int nodeA = node0 + r, nodeB = node0 + r + 4;
    if (nodeA < n) xlp[(size_t)nodeA * HID + j] = __float2bfloat16(dinv[nodeA] * acc0);
    if (nodeB < n) xlp[(size_t)nodeB * HID + j] = __float2bfloat16(dinv[nodeB] * acc1);
}

// hout[d] = relu(dd*(sum_s xlp[s] + xlp[d]) + b1), bf16 gathers.
// One wave per dst; two 32-lane halves process alternating edges; 4-deep unroll/half.
__global__ __launch_bounds__(256) void k_agg1(const int* __restrict__ rowptr,
                                              const int* __restrict__ counts,
                                              const int* __restrict__ esrc,
                                              const float* __restrict__ dinv,
                                              const __hip_bfloat16* __restrict__ xlp,
                                              const float* __restrict__ b,
                                              float* __restrict__ hout, int n) {
    int d = blockIdx.x * 4 + (threadIdx.x >> 6);
    if (d >= n) return;
    int lane = threadIdx.x & 63;
    int hf = lane >> 5;      // half: 0 = even edges, 1 = odd edges
    int cl = lane & 31;      // channel pair -> ch {2cl, 2cl+1}
    int j0 = rowptr[d];
    int cnt = counts[d];
    float a0 = 0.f, a1 = 0.f;
    int t = 0;
    for (; t + 8 <= cnt; t += 8) {
        int base = j0 + t + hf;
        int s0 = esrc[base], s1 = esrc[base + 2], s2 = esrc[base + 4], s3 = esrc[base + 6];
        unsigned w0 = ((const unsigned*)(xlp + (size_t)s0 * HID))[cl];
        unsigned w1 = ((const unsigned*)(xlp + (size_t)s1 * HID))[cl];
        unsigned w2 = ((const unsigned*)(xlp + (size_t)s2 * HID))[cl];
        unsigned w3 = ((const unsigned*)(xlp + (size_t)s3 * HID))[cl];
        a0 += (__uint_as_float(w0 << 16) + __uint_as_float(w1 << 16)) +
              (__uint_as_float(w2 << 16) + __uint_as_float(w3 << 16));
        a1 += (__uint_as_float(w0 & 0xffff0000u) + __uint_as_float(w1 & 0xffff0000u)) +
              (__uint_as_float(w2 & 0xffff0000u) + __uint_as_float(w3 & 0xffff0000u));
    }
    for (; t < cnt; ++t) {
        if ((t & 1) == hf) {
            int s = esrc[j0 + t];
            unsigned w = ((const unsigned*)(xlp + (size_t)s * HID))[cl];
            a0 += __uint_as_float(w << 16);
            a1 += __uint_as_float(w & 0xffff0000u);
        }
    }
    // combine the two halves
    a0 += __shfl_xor(a0, 32);
    a1 += __shfl_xor(a1, 32);
    if (hf == 0) {
        unsigned ws = ((const unsigned*)(xlp + (size_t)d * HID))[cl];  // self-loop
        float dd = dinv[d];
        float v0 = dd * (a0 + __uint_as_float(ws << 16)) + b[2 * cl];
        float v1 = dd * (a1 + __uint_as_float(ws & 0xffff0000u)) + b[2 * cl + 1];
        ((float2*)(hout + (size_t)d * HID))[cl] = make_float2(fmaxf(v0, 0.f), fmaxf(v1, 0.f));
    }
}

// ---------------- layer 2 ----------------

// hlp = dinv * (h @ W2); 16 nodes/block (fp32 throughout)
__global__ __launch_bounds__(256) void k_gemm2(const float* __restrict__ h,
                                               const float* __restrict__ W,
                                               const float* __restrict__ dinv,
                                               float* __restrict__ hlp, int n) {
    __shared__ float sW[HID * OUT_CH];
    __shared__ float sh[16][HID];
    int tid = threadIdx.x;
    for (int t = tid; t < HID * OUT_CH; t += 256) sW[t] = W[t];
    int node0 = blockIdx.x * 16;
    for (int t = tid; t < 16 * HID / 4; t += 256) {
        int r = t >> 4, k4 = t & 15;
        int node = node0 + r;
        float4 v = (node < n) ? ((const float4*)(h + (size_t)node * HID))[k4]
                              : make_float4(0.f, 0.f, 0.f, 0.f);
        ((float4*)sh[r])[k4] = v;
    }
    __syncthreads();
    int r = tid >> 4, j = tid & 15;
    int node = node0 + r;
    if (node >= n) return;
    float acc = 0.f;
#pragma unroll
    for (int k = 0; k < HID; ++k)
        acc += sh[r][k] * sW[k * OUT_CH + j];
    hlp[(size_t)node * OUT_CH + j] = dinv[node] * acc;
}

// out[d] = dd * (sum_s hlp[s] + hlp[d]) + b2. One 16-lane group per dst; 4-edge unroll.
__global__ __launch_bounds__(256) void k_agg2(const int* __restrict__ rowptr,
                                              const int* __restrict__ counts,
                                              const int* __restrict__ esrc,
                                              const float* __restrict__ dinv,
                                              const float* __restrict__ hlp,
                                              const float* __restrict__ b,
                                              float* __restrict__ out, int n) {
    int d = blockIdx.x * 16 + (threadIdx.x >> 4);
    int c = threadIdx.x & 15;
    if (d >= n) return;
    int j0 = rowptr[d], j1 = j0 + counts[d];
    float acc = 0.f;
    int j = j0;
    for (; j + 4 <= j1; j += 4) {
        int s0 = esrc[j], s1 = esrc[j + 1], s2 = esrc[j + 2], s3 = esrc[j + 3];
        float v0 = hlp[(size_t)s0 * OUT_CH + c];
        float v1 = hlp[(size_t)s1 * OUT_CH + c];
        float v2 = hlp[(size_t)s2 * OUT_CH + c];
        float v3 = hlp[(size_t)s3 * OUT_CH + c];
        acc += (v0 + v1) + (v2 + v3);
    }
    for (; j < j1; ++j) acc += hlp[(size_t)esrc[j] * OUT_CH + c];
    float dd = dinv[d];
    out[(size_t)d * OUT_CH + c] = dd * (acc + hlp[(size_t)d * OUT_CH + c]) + b[c];
}

extern "C" void kernel_launch(void* const* d_in, const int* in_sizes, int n_in,
                              void* d_out, int out_size, void* d_ws, size_t ws_size,
                              hipStream_t stream) {
    const float* x  = (const float*)d_in[0];
    const int* ei   = (const int*)d_in[1];   // int32 from harness
    const float* W1 = (const float*)d_in[2];
    const float* b1 = (const float*)d_in[3];
    const float* W2 = (const float*)d_in[4];
    const float* b2 = (const float*)d_in[5];
    float* out = (float*)d_out;

    const int n = in_sizes[0] / IN_CH;      // 100000
    const int E = in_sizes[1] / 2;          // 1600000
    const int nblk = (n + 255) / 256;       // 391
    const int nb = (n + G_SZ - 1) >> G_SH;  // 782 buckets

    // workspace (ints): counts n | rowptr n | blk 512 | bcursor 1024 | packed E |
    //   dinv n | xlp 32n (bf16 64/node, aliased by hlp f32 16/node) | hout 64n
    //   total = 99n + E + 1536 ints ~= 46 MB
    int* counts  = (int*)d_ws;
    int* rowptr  = counts + n;
    int* blk     = rowptr + n;
    int* bcursor = blk + 512;
    int* packed  = bcursor + 1024;
    float* dinv  = (float*)(packed + E);
    __hip_bfloat16* xlp = (__hip_bfloat16*)(dinv + n);  // n*64 bf16
    float* hlp   = (float*)xlp;                          // alias: xlp dead after k_agg1
    float* hout  = (float*)(xlp + (size_t)n * HID);      // n*64 f32

    // degree + rowptr + dinv + bucket cursors
    k_zero_int<<<nblk, 256, 0, stream>>>(counts, n);
    k_count<<<(E + 255) / 256, 256, 0, stream>>>(ei, counts, E);
    k_scan_local<<<nblk, 256, 0, stream>>>(counts, rowptr, blk, dinv, n);
    k_scan_blocks<<<1, 256, 0, stream>>>(blk, nblk);
    k_scan_add<<<nblk, 256, 0, stream>>>(rowptr, blk, bcursor, n);

    // coarse bucket sort + per-bucket fine sort (in place -> CSR-ordered src ids)
    k_bucket<<<(E + CHUNK - 1) / CHUNK, 256, 0, stream>>>(ei, bcursor, packed, E, nb);
    k_sortbkt<<<nb, 256, 0, stream>>>(rowptr, counts, packed, n);

    // layer 1
    k_gemm1<<<(n + 7) / 8, 256, 0, stream>>>(x, W1, dinv, xlp, n);
    k_agg1<<<(n + 3) / 4, 256, 0, stream>>>(rowptr, counts, packed, dinv, xlp, b1, hout, n);

    // layer 2
    k_gemm2<<<(n + 15) / 16, 256, 0, stream>>>(hout, W2, dinv, hlp, n);
    k_agg2<<<(n + 15) / 16, 256, 0, stream>>>(rowptr, counts, packed, dinv, hlp, b2, out, n);
}

// Round 9
// 187.853 us; speedup vs baseline: 2.0228x; 1.4986x over previous
//
#include <hip/hip_runtime.h>
#include <hip/hip_bf16.h>

#define IN_CH 128
#define HID 64
#define OUT_CH 16

#define G_SH 7
#define G_SZ 128          // dst nodes per bucket
#define NBK_MAX 800       // max buckets (n <= 102400)
#define CHUNK 4096        // edges per bucketing block
#define SORT_CAP 4096     // max edges per bucket (mean 2048, std ~45)

__device__ __forceinline__ float bf_lo(unsigned w) { return __uint_as_float(w << 16); }
__device__ __forceinline__ float bf_hi(unsigned w) { return __uint_as_float(w & 0xffff0000u); }

// ---------------- bucket counts ----------------

__global__ void k_zero_int(int* __restrict__ p, int n) {
    int i = blockIdx.x * blockDim.x + threadIdx.x;
    if (i < n) p[i] = 0;
}

// per-block LDS histogram of dst>>7, flushed with one atomic per nonzero bucket
__global__ __launch_bounds__(256) void k_bcnt(const int* __restrict__ dst,
                                              int* __restrict__ bcnt, int E, int nb) {
    __shared__ int hist[NBK_MAX];
    int tid = threadIdx.x;
    for (int t = tid; t < nb; t += 256) hist[t] = 0;
    __syncthreads();
    int base = blockIdx.x * CHUNK;
    int end = base + CHUNK; if (end > E) end = E;
    for (int i = base + tid; i < end; i += 256)
        atomicAdd(&hist[dst[i] >> G_SH], 1);
    __syncthreads();
    for (int t = tid; t < nb; t += 256)
        if (hist[t]) atomicAdd(&bcnt[t], hist[t]);
}

// single-block exclusive scan of bucket counts -> boff (nb+1) and bcursor copy
__global__ __launch_bounds__(256) void k_scan_small(const int* __restrict__ bcnt,
                                                    int* __restrict__ boff,
                                                    int* __restrict__ bcursor, int nb) {
    __shared__ int s[256];
    __shared__ int carry;
    if (threadIdx.x == 0) carry = 0;
    __syncthreads();
    for (int base = 0; base < nb; base += 256) {
        int i = base + threadIdx.x;
        int v = (i < nb) ? bcnt[i] : 0;
        s[threadIdx.x] = v;
        __syncthreads();
        for (int off = 1; off < 256; off <<= 1) {
            int t = (threadIdx.x >= off) ? s[threadIdx.x - off] : 0;
            __syncthreads();
            s[threadIdx.x] += t;
            __syncthreads();
        }
        if (i < nb) {
            int ex = carry + s[threadIdx.x] - v;
            boff[i] = ex;
            bcursor[i] = ex;
        }
        __syncthreads();
        if (threadIdx.x == 255) carry += s[255];
        __syncthreads();
    }
    if (threadIdx.x == 0) boff[nb] = carry;
}

// ---------------- edge bucketing (coarse sort by dst>>7) ----------------
// packed word: (d_local << 17) | src   (src < 2^17)
__global__ __launch_bounds__(256) void k_bucket(const int* __restrict__ ei,
                                                int* __restrict__ bcursor,
                                                int* __restrict__ packed, int E, int nb) {
    __shared__ int hcnt[NBK_MAX];
    __shared__ int hoff[NBK_MAX];
    __shared__ int hbase[NBK_MAX];
    __shared__ int hcur[NBK_MAX];
    __shared__ int stage[CHUNK];
    __shared__ unsigned short sbk[CHUNK];
    __shared__ int scan_s[256];
    __shared__ int sh_carry;

    int tid = threadIdx.x;
    int base = blockIdx.x * CHUNK;
    int cnt = E - base;
    if (cnt > CHUNK) cnt = CHUNK;
    for (int t = tid; t < nb; t += 256) { hcnt[t] = 0; hcur[t] = 0; }
    if (tid == 0) sh_carry = 0;
    __syncthreads();

    int mp[CHUNK / 256], mb[CHUNK / 256];
#pragma unroll
    for (int k = 0; k < CHUNK / 256; ++k) {
        int idx = base + k * 256 + tid;
        int p = 0, b = -1;
        if (idx < E) {
            int s = ei[idx];
            int d = ei[E + idx];
            b = d >> G_SH;
            p = ((d & (G_SZ - 1)) << 17) | s;
            atomicAdd(&hcnt[b], 1);
        }
        mp[k] = p; mb[k] = b;
    }
    __syncthreads();

    // exclusive scan of hcnt -> hoff
    for (int s0 = 0; s0 < nb; s0 += 256) {
        int i = s0 + tid;
        int v = (i < nb) ? hcnt[i] : 0;
        scan_s[tid] = v;
        __syncthreads();
        for (int off = 1; off < 256; off <<= 1) {
            int t = (tid >= off) ? scan_s[tid - off] : 0;
            __syncthreads();
            scan_s[tid] += t;
            __syncthreads();
        }
        if (i < nb) hoff[i] = sh_carry + scan_s[tid] - v;
        __syncthreads();
        if (tid == 255) sh_carry += scan_s[255];
        __syncthreads();
    }

    // reserve global space per bucket
    for (int t = tid; t < nb; t += 256)
        if (hcnt[t] > 0) hbase[t] = atomicAdd(&bcursor[t], hcnt[t]);
    __syncthreads();

    // LDS scatter into bucket-ordered staging
#pragma unroll
    for (int k = 0; k < CHUNK / 256; ++k) {
        int b = mb[k];
        if (b >= 0) {
            int slot = hoff[b] + atomicAdd(&hcur[b], 1);
            stage[slot] = mp[k];
            sbk[slot] = (unsigned short)b;
        }
    }
    __syncthreads();

    // coalesced run write-out
    for (int i = tid; i < cnt; i += 256) {
        int b = sbk[i];
        packed[hbase[b] + (i - hoff[b])] = stage[i];
    }
}

// ---- per-bucket fine counting sort; also emits rowptr/counts/dinv per node ----

__global__ __launch_bounds__(256) void k_sortbkt(const int* __restrict__ boff,
                                                 int* __restrict__ packed,
                                                 int* __restrict__ rowptr,
                                                 int* __restrict__ counts,
                                                 float* __restrict__ dinv, int n) {
    __shared__ int sc[G_SZ];
    __shared__ int lcur[G_SZ];
    __shared__ int stage[SORT_CAP];
    __shared__ int sorted_[SORT_CAP];

    int tid = threadIdx.x;
    int bkt = blockIdx.x;
    int d0 = bkt << G_SH;
    int j0 = boff[bkt], j1 = boff[bkt + 1];
    int L = j1 - j0;

    if (tid < G_SZ) sc[tid] = 0;
    __syncthreads();
    // load + histogram in one pass
    for (int i = tid; i < L; i += 256) {
        int p = packed[j0 + i];
        stage[i] = p;
        atomicAdd(&sc[p >> 17], 1);
    }
    __syncthreads();
    int v = (tid < G_SZ) ? sc[tid] : 0;
    // inclusive Hillis-Steele over 128
    for (int off = 1; off < G_SZ; off <<= 1) {
        int t = (tid < G_SZ && tid >= off) ? sc[tid - off] : 0;
        __syncthreads();
        if (tid < G_SZ) sc[tid] += t;
        __syncthreads();
    }
    if (tid < G_SZ) {
        int excl = sc[tid] - v;
        lcur[tid] = excl;
        int d = d0 + tid;
        if (d < n) {
            rowptr[d] = j0 + excl;
            counts[d] = v;
            dinv[d] = rsqrtf((float)(v + 1));  // +1 = self-loop
        }
    }
    __syncthreads();
    for (int i = tid; i < L; i += 256) {
        int p = stage[i];
        int pos = atomicAdd(&lcur[p >> 17], 1);
        sorted_[pos] = p & 0x1FFFF;
    }
    __syncthreads();
    for (int i = tid; i < L; i += 256) packed[j0 + i] = sorted_[i];
}

// ---------------- layer 1 ----------------

// xlp = bf16(dinv * (x @ W1)); 32 nodes/block, 8 nodes/thread (8 FMA per W load)
__global__ __launch_bounds__(256) void k_gemm1(const float* __restrict__ x,
                                               const float* __restrict__ W,
                                               const float* __restrict__ dinv,
                                               __hip_bfloat16* __restrict__ xlp, int n) {
    __shared__ float sx[32][IN_CH];  // 16 KB
    int node0 = blockIdx.x * 32;
    int tid = threadIdx.x;
    for (int i = tid; i < 32 * IN_CH / 4; i += 256) {
        int r = i >> 5, k4 = i & 31;
        int node = node0 + r;
        float4 v = (node < n) ? ((const float4*)(x + (size_t)node * IN_CH))[k4]
                              : make_float4(0.f, 0.f, 0.f, 0.f);
        ((float4*)sx[r])[k4] = v;
    }
    __syncthreads();
    int r = tid >> 6;   // wave id 0..3
    int j = tid & 63;   // output channel
    float acc[8] = {0.f, 0.f, 0.f, 0.f, 0.f, 0.f, 0.f, 0.f};
#pragma unroll 4
    for (int k = 0; k < IN_CH; ++k) {
        float w = W[k * HID + j];
#pragma unroll
        for (int u = 0; u < 8; ++u)
            acc[u] += sx[r + 4 * u][k] * w;  // LDS broadcast per u
    }
#pragma unroll
    for (int u = 0; u < 8; ++u) {
        int node = node0 + r + 4 * u;
        if (node < n)
            xlp[(size_t)node * HID + j] = __float2bfloat16(dinv[node] * acc[u]);
    }
}

// hout[d] = relu(dd*(sum_s xlp[s] + xlp[d]) + b1), bf16 gathers.
// One 32-lane group per dst (cl = channel pair); 8-deep edge unroll.
__global__ __launch_bounds__(256) void k_agg1(const int* __restrict__ rowptr,
                                              const int* __restrict__ counts,
                                              const int* __restrict__ esrc,
                                              const float* __restrict__ dinv,
                                              const __hip_bfloat16* __restrict__ xlp,
                                              const float* __restrict__ b,
                                              float* __restrict__ hout, int n) {
    int d = blockIdx.x * 8 + (threadIdx.x >> 5);
    if (d >= n) return;
    int cl = threadIdx.x & 31;  // uint index -> channels {2cl, 2cl+1}
    int j0 = rowptr[d];
    int cnt = counts[d];
    float a0 = 0.f, a1 = 0.f;
    int t = 0;
    for (; t + 8 <= cnt; t += 8) {
        int s0 = esrc[j0 + t],     s1 = esrc[j0 + t + 1];
        int s2 = esrc[j0 + t + 2], s3 = esrc[j0 + t + 3];
        int s4 = esrc[j0 + t + 4], s5 = esrc[j0 + t + 5];
        int s6 = esrc[j0 + t + 6], s7 = esrc[j0 + t + 7];
        unsigned w0 = ((const unsigned*)(xlp + (size_t)s0 * HID))[cl];
        unsigned w1 = ((const unsigned*)(xlp + (size_t)s1 * HID))[cl];
        unsigned w2 = ((const unsigned*)(xlp + (size_t)s2 * HID))[cl];
        unsigned w3 = ((const unsigned*)(xlp + (size_t)s3 * HID))[cl];
        unsigned w4 = ((const unsigned*)(xlp + (size_t)s4 * HID))[cl];
        unsigned w5 = ((const unsigned*)(xlp + (size_t)s5 * HID))[cl];
        unsigned w6 = ((const unsigned*)(xlp + (size_t)s6 * HID))[cl];
        unsigned w7 = ((const unsigned*)(xlp + (size_t)s7 * HID))[cl];
        a0 += ((bf_lo(w0) + bf_lo(w1)) + (bf_lo(w2) + bf_lo(w3))) +
              ((bf_lo(w4) + bf_lo(w5)) + (bf_lo(w6) + bf_lo(w7)));
        a1 += ((bf_hi(w0) + bf_hi(w1)) + (bf_hi(w2) + bf_hi(w3))) +
              ((bf_hi(w4) + bf_hi(w5)) + (bf_hi(w6) + bf_hi(w7)));
    }
    for (; t + 4 <= cnt; t += 4) {
        int s0 = esrc[j0 + t],     s1 = esrc[j0 + t + 1];
        int s2 = esrc[j0 + t + 2], s3 = esrc[j0 + t + 3];
        unsigned w0 = ((const unsigned*)(xlp + (size_t)s0 * HID))[cl];
        unsigned w1 = ((const unsigned*)(xlp + (size_t)s1 * HID))[cl];
        unsigned w2 = ((const unsigned*)(xlp + (size_t)s2 * HID))[cl];
        unsigned w3 = ((const unsigned*)(xlp + (size_t)s3 * HID))[cl];
        a0 += (bf_lo(w0) + bf_lo(w1)) + (bf_lo(w2) + bf_lo(w3));
        a1 += (bf_hi(w0) + bf_hi(w1)) + (bf_hi(w2) + bf_hi(w3));
    }
    for (; t < cnt; ++t) {
        int s = esrc[j0 + t];
        unsigned w = ((const unsigned*)(xlp + (size_t)s * HID))[cl];
        a0 += bf_lo(w);
        a1 += bf_hi(w);
    }
    unsigned ws = ((const unsigned*)(xlp + (size_t)d * HID))[cl];  // self-loop
    float dd = dinv[d];
    float v0 = dd * (a0 + bf_lo(ws)) + b[2 * cl];
    float v1 = dd * (a1 + bf_hi(ws)) + b[2 * cl + 1];
    ((float2*)(hout + (size_t)d * HID))[cl] = make_float2(fmaxf(v0, 0.f), fmaxf(v1, 0.f));
}

// ---------------- layer 2 ----------------

// hlp = bf16(dinv * (h @ W2)); 16 nodes/block
__global__ __launch_bounds__(256) void k_gemm2(const float* __restrict__ h,
                                               const float* __restrict__ W,
                                               const float* __restrict__ dinv,
                                               __hip_bfloat16* __restrict__ hlp, int n) {
    __shared__ float sW[HID * OUT_CH];
    __shared__ float sh[16][HID];
    int tid = threadIdx.x;
    for (int t = tid; t < HID * OUT_CH; t += 256) sW[t] = W[t];
    int node0 = blockIdx.x * 16;
    for (int t = tid; t < 16 * HID / 4; t += 256) {
        int r = t >> 4, k4 = t & 15;
        int node = node0 + r;
        float4 v = (node < n) ? ((const float4*)(h + (size_t)node * HID))[k4]
                              : make_float4(0.f, 0.f, 0.f, 0.f);
        ((float4*)sh[r])[k4] = v;
    }
    __syncthreads();
    int r = tid >> 4, j = tid & 15;
    int node = node0 + r;
    if (node >= n) return;
    float acc = 0.f;
#pragma unroll
    for (int k = 0; k < HID; ++k)
        acc += sh[r][k] * sW[k * OUT_CH + j];
    hlp[(size_t)node * OUT_CH + j] = __float2bfloat16(dinv[node] * acc);
}

// out[d] = dd*(sum_s hlp[s] + hlp[d]) + b2, bf16 gathers from 3.2 MB table.
// One 8-lane group per dst; 8-deep unroll.
__global__ __launch_bounds__(256) void k_agg2(const int* __restrict__ rowptr,
                                              const int* __restrict__ counts,
                                              const int* __restrict__ esrc,
                                              const float* __restrict__ dinv,
                                              const __hip_bfloat16* __restrict__ hlp,
                                              const float* __restrict__ b,
                                              float* __restrict__ out, int n) {
    int d = blockIdx.x * 32 + (threadIdx.x >> 3);
    if (d >= n) return;
    int cl = threadIdx.x & 7;  // uint index -> channels {2cl, 2cl+1}
    int j0 = rowptr[d];
    int cnt = counts[d];
    float a0 = 0.f, a1 = 0.f;
    int t = 0;
    for (; t + 8 <= cnt; t += 8) {
        int s0 = esrc[j0 + t],     s1 = esrc[j0 + t + 1];
        int s2 = esrc[j0 + t + 2], s3 = esrc[j0 + t + 3];
        int s4 = esrc[j0 + t + 4], s5 = esrc[j0 + t + 5];
        int s6 = esrc[j0 + t + 6], s7 = esrc[j0 + t + 7];
        unsigned w0 = ((const unsigned*)(hlp + (size_t)s0 * OUT_CH))[cl];
        unsigned w1 = ((const unsigned*)(hlp + (size_t)s1 * OUT_CH))[cl];
        unsigned w2 = ((const unsigned*)(hlp + (size_t)s2 * OUT_CH))[cl];
        unsigned w3 = ((const unsigned*)(hlp + (size_t)s3 * OUT_CH))[cl];
        unsigned w4 = ((const unsigned*)(hlp + (size_t)s4 * OUT_CH))[cl];
        unsigned w5 = ((const unsigned*)(hlp + (size_t)s5 * OUT_CH))[cl];
        unsigned w6 = ((const unsigned*)(hlp + (size_t)s6 * OUT_CH))[cl];
        unsigned w7 = ((const unsigned*)(hlp + (size_t)s7 * OUT_CH))[cl];
        a0 += ((bf_lo(w0) + bf_lo(w1)) + (bf_lo(w2) + bf_lo(w3))) +
              ((bf_lo(w4) + bf_lo(w5)) + (bf_lo(w6) + bf_lo(w7)));
        a1 += ((bf_hi(w0) + bf_hi(w1)) + (bf_hi(w2) + bf_hi(w3))) +
              ((bf_hi(w4) + bf_hi(w5)) + (bf_hi(w6) + bf_hi(w7)));
    }
    for (; t + 4 <= cnt; t += 4) {
        int s0 = esrc[j0 + t],     s1 = esrc[j0 + t + 1];
        int s2 = esrc[j0 + t + 2], s3 = esrc[j0 + t + 3];
        unsigned w0 = ((const unsigned*)(hlp + (size_t)s0 * OUT_CH))[cl];
        unsigned w1 = ((const unsigned*)(hlp + (size_t)s1 * OUT_CH))[cl];
        unsigned w2 = ((const unsigned*)(hlp + (size_t)s2 * OUT_CH))[cl];
        unsigned w3 = ((const unsigned*)(hlp + (size_t)s3 * OUT_CH))[cl];
        a0 += (bf_lo(w0) + bf_lo(w1)) + (bf_lo(w2) + bf_lo(w3));
        a1 += (bf_hi(w0) + bf_hi(w1)) + (bf_hi(w2) + bf_hi(w3));
    }
    for (; t < cnt; ++t) {
        int s = esrc[j0 + t];
        unsigned w = ((const unsigned*)(hlp + (size_t)s * OUT_CH))[cl];
        a0 += bf_lo(w);
        a1 += bf_hi(w);
    }
    unsigned ws = ((const unsigned*)(hlp + (size_t)d * OUT_CH))[cl];  // self-loop
    float dd = dinv[d];
    float v0 = dd * (a0 + bf_lo(ws)) + b[2 * cl];
    float v1 = dd * (a1 + bf_hi(ws)) + b[2 * cl + 1];
    ((float2*)(out + (size_t)d * OUT_CH))[cl] = make_float2(v0, v1);
}

extern "C" void kernel_launch(void* const* d_in, const int* in_sizes, int n_in,
                              void* d_out, int out_size, void* d_ws, size_t ws_size,
                              hipStream_t stream) {
    const float* x  = (const float*)d_in[0];
    const int* ei   = (const int*)d_in[1];   // int32 from harness
    const float* W1 = (const float*)d_in[2];
    const float* b1 = (const float*)d_in[3];
    const float* W2 = (const float*)d_in[4];
    const float* b2 = (const float*)d_in[5];
    float* out = (float*)d_out;

    const int n = in_sizes[0] / IN_CH;      // 100000
    const int E = in_sizes[1] / 2;          // 1600000
    const int nb = (n + G_SZ - 1) >> G_SH;  // 782 buckets
    const int nchunk = (E + CHUNK - 1) / CHUNK;

    // workspace (ints): rowptr n | counts n | bcnt 1024 | boff 1032 | bcursor 1024 |
    //   packed E | dinv n | xlp 32n (bf16 64/node; hlp bf16 16/node aliases) | hout 64n
    int* rowptr  = (int*)d_ws;
    int* counts  = rowptr + n;
    int* bcnt    = counts + n;
    int* boff    = bcnt + 1024;
    int* bcursor = boff + 1032;
    int* packed  = bcursor + 1024;
    float* dinv  = (float*)(packed + E);
    __hip_bfloat16* xlp = (__hip_bfloat16*)(dinv + n);   // n*64 bf16
    __hip_bfloat16* hlp = xlp;                            // alias: xlp dead after k_agg1
    float* hout  = (float*)(xlp + (size_t)n * HID);       // n*64 f32

    // CSR build: bucket counts -> scan -> coarse bucket -> fine sort (+rowptr/counts/dinv)
    k_zero_int<<<(nb + 255) / 256, 256, 0, stream>>>(bcnt, nb);
    k_bcnt<<<nchunk, 256, 0, stream>>>(ei + E, bcnt, E, nb);
    k_scan_small<<<1, 256, 0, stream>>>(bcnt, boff, bcursor, nb);
    k_bucket<<<nchunk, 256, 0, stream>>>(ei, bcursor, packed, E, nb);
    k_sortbkt<<<nb, 256, 0, stream>>>(boff, packed, rowptr, counts, dinv, n);

    // layer 1
    k_gemm1<<<(n + 31) / 32, 256, 0, stream>>>(x, W1, dinv, xlp, n);
    k_agg1<<<(n + 7) / 8, 256, 0, stream>>>(rowptr, counts, packed, dinv, xlp, b1, hout, n);

    // layer 2
    k_gemm2<<<(n + 15) / 16, 256, 0, stream>>>(hout, W2, dinv, hlp, n);
    k_agg2<<<(n + 31) / 32, 256, 0, stream>>>(rowptr, counts, packed, dinv, hlp, b2, out, n);
}

// Round 10
// 169.269 us; speedup vs baseline: 2.2449x; 1.1098x over previous
//
#include <hip/hip_runtime.h>
#include <hip/hip_bf16.h>

#define IN_CH 128
#define HID 64
#define OUT_CH 16

#define G_SH 7
#define G_SZ 128          // dst nodes per bucket
#define NBK_MAX 800       // max buckets (n <= 102400)
#define CHUNK 4096        // edges per bucketing block
#define CAP 4096          // fixed capacity per bucket (mean 2048, sigma ~45)

__device__ __forceinline__ float bf_lo(unsigned w) { return __uint_as_float(w << 16); }
__device__ __forceinline__ float bf_hi(unsigned w) { return __uint_as_float(w & 0xffff0000u); }

__device__ __forceinline__ unsigned pack_bf2(float lo, float hi) {
    __hip_bfloat16 l = __float2bfloat16(lo), h = __float2bfloat16(hi);
    unsigned short ls, hs;
    __builtin_memcpy(&ls, &l, 2);
    __builtin_memcpy(&hs, &h, 2);
    return ((unsigned)hs << 16) | (unsigned)ls;
}

// ---------------- bucket cursors ----------------

__global__ void k_init_bcur(int* __restrict__ p, int nb) {
    int i = blockIdx.x * blockDim.x + threadIdx.x;
    if (i < nb) p[i] = i * CAP;
}

// ---------------- edge bucketing (coarse sort by dst>>7) ----------------
// packed word: (d_local << 17) | src   (src < 2^17)
__global__ __launch_bounds__(256) void k_bucket(const int* __restrict__ ei,
                                                int* __restrict__ bcursor,
                                                int* __restrict__ packed, int E, int nb) {
    __shared__ int hcnt[NBK_MAX];
    __shared__ int hoff[NBK_MAX];
    __shared__ int hbase[NBK_MAX];
    __shared__ int hcur[NBK_MAX];
    __shared__ int stage[CHUNK];
    __shared__ unsigned short sbk[CHUNK];
    __shared__ int scan_s[256];
    __shared__ int sh_carry;

    int tid = threadIdx.x;
    int base = blockIdx.x * CHUNK;
    int cnt = E - base;
    if (cnt > CHUNK) cnt = CHUNK;
    for (int t = tid; t < nb; t += 256) { hcnt[t] = 0; hcur[t] = 0; }
    if (tid == 0) sh_carry = 0;
    __syncthreads();

    int mp[CHUNK / 256], mb[CHUNK / 256];
#pragma unroll
    for (int k = 0; k < CHUNK / 256; ++k) {
        int idx = base + k * 256 + tid;
        int p = 0, b = -1;
        if (idx < E) {
            int s = ei[idx];
            int d = ei[E + idx];
            b = d >> G_SH;
            p = ((d & (G_SZ - 1)) << 17) | s;
            atomicAdd(&hcnt[b], 1);
        }
        mp[k] = p; mb[k] = b;
    }
    __syncthreads();

    // exclusive scan of hcnt -> hoff
    for (int s0 = 0; s0 < nb; s0 += 256) {
        int i = s0 + tid;
        int v = (i < nb) ? hcnt[i] : 0;
        scan_s[tid] = v;
        __syncthreads();
        for (int off = 1; off < 256; off <<= 1) {
            int t = (tid >= off) ? scan_s[tid - off] : 0;
            __syncthreads();
            scan_s[tid] += t;
            __syncthreads();
        }
        if (i < nb) hoff[i] = sh_carry + scan_s[tid] - v;
        __syncthreads();
        if (tid == 255) sh_carry += scan_s[255];
        __syncthreads();
    }

    // reserve space in fixed-capacity bucket regions
    for (int t = tid; t < nb; t += 256)
        if (hcnt[t] > 0) hbase[t] = atomicAdd(&bcursor[t], hcnt[t]);
    __syncthreads();

    // LDS scatter into bucket-ordered staging
#pragma unroll
    for (int k = 0; k < CHUNK / 256; ++k) {
        int b = mb[k];
        if (b >= 0) {
            int slot = hoff[b] + atomicAdd(&hcur[b], 1);
            stage[slot] = mp[k];
            sbk[slot] = (unsigned short)b;
        }
    }
    __syncthreads();

    // coalesced run write-out
    for (int i = tid; i < cnt; i += 256) {
        int b = sbk[i];
        packed[hbase[b] + (i - hoff[b])] = stage[i];
    }
}

// ---- per-bucket fine counting sort; emits rowptr/counts/dinv per node ----

__global__ __launch_bounds__(256) void k_sortbkt(const int* __restrict__ bcursor,
                                                 int* __restrict__ packed,
                                                 int* __restrict__ rowptr,
                                                 int* __restrict__ counts,
                                                 float* __restrict__ dinv, int n) {
    __shared__ int sc[G_SZ];
    __shared__ int lcur[G_SZ];
    __shared__ int stage[CAP];
    __shared__ int sorted_[CAP];

    int tid = threadIdx.x;
    int bkt = blockIdx.x;
    int d0 = bkt << G_SH;
    int base = bkt * CAP;
    int L = bcursor[bkt] - base;

    if (tid < G_SZ) sc[tid] = 0;
    __syncthreads();
    // load + histogram in one pass
    for (int i = tid; i < L; i += 256) {
        int p = packed[base + i];
        stage[i] = p;
        atomicAdd(&sc[p >> 17], 1);
    }
    __syncthreads();
    int v = (tid < G_SZ) ? sc[tid] : 0;
    // inclusive Hillis-Steele over 128
    for (int off = 1; off < G_SZ; off <<= 1) {
        int t = (tid < G_SZ && tid >= off) ? sc[tid - off] : 0;
        __syncthreads();
        if (tid < G_SZ) sc[tid] += t;
        __syncthreads();
    }
    if (tid < G_SZ) {
        int excl = sc[tid] - v;
        lcur[tid] = excl;
        int d = d0 + tid;
        if (d < n) {
            rowptr[d] = base + excl;
            counts[d] = v;
            dinv[d] = rsqrtf((float)(v + 1));  // +1 = self-loop
        }
    }
    __syncthreads();
    for (int i = tid; i < L; i += 256) {
        int p = stage[i];
        int pos = atomicAdd(&lcur[p >> 17], 1);
        sorted_[pos] = p & 0x1FFFF;
    }
    __syncthreads();
    for (int i = tid; i < L; i += 256) packed[base + i] = sorted_[i];
}

// ---------------- layer 1 ----------------

// xlp = bf16(dinv * (x @ W1)); 32 nodes/block.
// Per wave: 2 half-waves x 4 nodes; lane = channel pair (float2 W loads).
__global__ __launch_bounds__(256) void k_gemm1(const float* __restrict__ x,
                                               const float* __restrict__ W,
                                               const float* __restrict__ dinv,
                                               __hip_bfloat16* __restrict__ xlp, int n) {
    __shared__ float sx[32][IN_CH];  // 16 KB
    int node0 = blockIdx.x * 32;
    int tid = threadIdx.x;
    for (int i = tid; i < 32 * IN_CH / 4; i += 256) {
        int r = i >> 5, k4 = i & 31;
        int node = node0 + r;
        float4 v = (node < n) ? ((const float4*)(x + (size_t)node * IN_CH))[k4]
                              : make_float4(0.f, 0.f, 0.f, 0.f);
        ((float4*)sx[r])[k4] = v;
    }
    __syncthreads();
    int w = tid >> 6;           // wave 0..3
    int lane = tid & 63;
    int hf = lane >> 5;         // half-wave: which 4 nodes
    int cl = lane & 31;         // channel pair -> ch {2cl, 2cl+1}
    int nbase = w * 8 + hf * 4;
    float2 a0 = {0.f, 0.f}, a1 = {0.f, 0.f}, a2 = {0.f, 0.f}, a3 = {0.f, 0.f};
#pragma unroll 4
    for (int k = 0; k < IN_CH; ++k) {
        float2 wv = *(const float2*)&W[k * HID + 2 * cl];
        float x0 = sx[nbase + 0][k];
        float x1 = sx[nbase + 1][k];
        float x2 = sx[nbase + 2][k];
        float x3 = sx[nbase + 3][k];
        a0.x += x0 * wv.x; a0.y += x0 * wv.y;
        a1.x += x1 * wv.x; a1.y += x1 * wv.y;
        a2.x += x2 * wv.x; a2.y += x2 * wv.y;
        a3.x += x3 * wv.x; a3.y += x3 * wv.y;
    }
#pragma unroll
    for (int u = 0; u < 4; ++u) {
        int node = node0 + nbase + u;
        if (node < n) {
            float dd = dinv[node];
            float2 av = (u == 0) ? a0 : (u == 1) ? a1 : (u == 2) ? a2 : a3;
            ((unsigned*)(xlp + (size_t)node * HID))[cl] =
                pack_bf2(dd * av.x, dd * av.y);
        }
    }
}

// hout[d] = relu(dd*(sum_s xlp[s] + xlp[d]) + b1), bf16 gathers.
// One 32-lane group per dst (cl = channel pair); 8-deep edge unroll.
__global__ __launch_bounds__(256) void k_agg1(const int* __restrict__ rowptr,
                                              const int* __restrict__ counts,
                                              const int* __restrict__ esrc,
                                              const float* __restrict__ dinv,
                                              const __hip_bfloat16* __restrict__ xlp,
                                              const float* __restrict__ b,
                                              float* __restrict__ hout, int n) {
    int d = blockIdx.x * 8 + (threadIdx.x >> 5);
    if (d >= n) return;
    int cl = threadIdx.x & 31;  // uint index -> channels {2cl, 2cl+1}
    int j0 = rowptr[d];
    int cnt = counts[d];
    float a0 = 0.f, a1 = 0.f;
    int t = 0;
    for (; t + 8 <= cnt; t += 8) {
        int s0 = esrc[j0 + t],     s1 = esrc[j0 + t + 1];
        int s2 = esrc[j0 + t + 2], s3 = esrc[j0 + t + 3];
        int s4 = esrc[j0 + t + 4], s5 = esrc[j0 + t + 5];
        int s6 = esrc[j0 + t + 6], s7 = esrc[j0 + t + 7];
        unsigned w0 = ((const unsigned*)(xlp + (size_t)s0 * HID))[cl];
        unsigned w1 = ((const unsigned*)(xlp + (size_t)s1 * HID))[cl];
        unsigned w2 = ((const unsigned*)(xlp + (size_t)s2 * HID))[cl];
        unsigned w3 = ((const unsigned*)(xlp + (size_t)s3 * HID))[cl];
        unsigned w4 = ((const unsigned*)(xlp + (size_t)s4 * HID))[cl];
        unsigned w5 = ((const unsigned*)(xlp + (size_t)s5 * HID))[cl];
        unsigned w6 = ((const unsigned*)(xlp + (size_t)s6 * HID))[cl];
        unsigned w7 = ((const unsigned*)(xlp + (size_t)s7 * HID))[cl];
        a0 += ((bf_lo(w0) + bf_lo(w1)) + (bf_lo(w2) + bf_lo(w3))) +
              ((bf_lo(w4) + bf_lo(w5)) + (bf_lo(w6) + bf_lo(w7)));
        a1 += ((bf_hi(w0) + bf_hi(w1)) + (bf_hi(w2) + bf_hi(w3))) +
              ((bf_hi(w4) + bf_hi(w5)) + (bf_hi(w6) + bf_hi(w7)));
    }
    for (; t + 4 <= cnt; t += 4) {
        int s0 = esrc[j0 + t],     s1 = esrc[j0 + t + 1];
        int s2 = esrc[j0 + t + 2], s3 = esrc[j0 + t + 3];
        unsigned w0 = ((const unsigned*)(xlp + (size_t)s0 * HID))[cl];
        unsigned w1 = ((const unsigned*)(xlp + (size_t)s1 * HID))[cl];
        unsigned w2 = ((const unsigned*)(xlp + (size_t)s2 * HID))[cl];
        unsigned w3 = ((const unsigned*)(xlp + (size_t)s3 * HID))[cl];
        a0 += (bf_lo(w0) + bf_lo(w1)) + (bf_lo(w2) + bf_lo(w3));
        a1 += (bf_hi(w0) + bf_hi(w1)) + (bf_hi(w2) + bf_hi(w3));
    }
    for (; t < cnt; ++t) {
        int s = esrc[j0 + t];
        unsigned w = ((const unsigned*)(xlp + (size_t)s * HID))[cl];
        a0 += bf_lo(w);
        a1 += bf_hi(w);
    }
    unsigned ws = ((const unsigned*)(xlp + (size_t)d * HID))[cl];  // self-loop
    float dd = dinv[d];
    float v0 = dd * (a0 + bf_lo(ws)) + b[2 * cl];
    float v1 = dd * (a1 + bf_hi(ws)) + b[2 * cl + 1];
    ((float2*)(hout + (size_t)d * HID))[cl] = make_float2(fmaxf(v0, 0.f), fmaxf(v1, 0.f));
}

// ---------------- layer 2 ----------------

// hlp = bf16(dinv * (h @ W2)); 16 nodes/block
__global__ __launch_bounds__(256) void k_gemm2(const float* __restrict__ h,
                                               const float* __restrict__ W,
                                               const float* __restrict__ dinv,
                                               __hip_bfloat16* __restrict__ hlp, int n) {
    __shared__ float sW[HID * OUT_CH];
    __shared__ float sh[16][HID];
    int tid = threadIdx.x;
    for (int t = tid; t < HID * OUT_CH; t += 256) sW[t] = W[t];
    int node0 = blockIdx.x * 16;
    for (int t = tid; t < 16 * HID / 4; t += 256) {
        int r = t >> 4, k4 = t & 15;
        int node = node0 + r;
        float4 v = (node < n) ? ((const float4*)(h + (size_t)node * HID))[k4]
                              : make_float4(0.f, 0.f, 0.f, 0.f);
        ((float4*)sh[r])[k4] = v;
    }
    __syncthreads();
    int r = tid >> 4, j = tid & 15;
    int node = node0 + r;
    if (node >= n) return;
    float acc = 0.f;
#pragma unroll
    for (int k = 0; k < HID; ++k)
        acc += sh[r][k] * sW[k * OUT_CH + j];
    hlp[(size_t)node * OUT_CH + j] = __float2bfloat16(dinv[node] * acc);
}

// out[d] = dd*(sum_s hlp[s] + hlp[d]) + b2, bf16 gathers from 3.2 MB table.
// One 8-lane group per dst; 8-deep unroll.
__global__ __launch_bounds__(256) void k_agg2(const int* __restrict__ rowptr,
                                              const int* __restrict__ counts,
                                              const int* __restrict__ esrc,
                                              const float* __restrict__ dinv,
                                              const __hip_bfloat16* __restrict__ hlp,
                                              const float* __restrict__ b,
                                              float* __restrict__ out, int n) {
    int d = blockIdx.x * 32 + (threadIdx.x >> 3);
    if (d >= n) return;
    int cl = threadIdx.x & 7;  // uint index -> channels {2cl, 2cl+1}
    int j0 = rowptr[d];
    int cnt = counts[d];
    float a0 = 0.f, a1 = 0.f;
    int t = 0;
    for (; t + 8 <= cnt; t += 8) {
        int s0 = esrc[j0 + t],     s1 = esrc[j0 + t + 1];
        int s2 = esrc[j0 + t + 2], s3 = esrc[j0 + t + 3];
        int s4 = esrc[j0 + t + 4], s5 = esrc[j0 + t + 5];
        int s6 = esrc[j0 + t + 6], s7 = esrc[j0 + t + 7];
        unsigned w0 = ((const unsigned*)(hlp + (size_t)s0 * OUT_CH))[cl];
        unsigned w1 = ((const unsigned*)(hlp + (size_t)s1 * OUT_CH))[cl];
        unsigned w2 = ((const unsigned*)(hlp + (size_t)s2 * OUT_CH))[cl];
        unsigned w3 = ((const unsigned*)(hlp + (size_t)s3 * OUT_CH))[cl];
        unsigned w4 = ((const unsigned*)(hlp + (size_t)s4 * OUT_CH))[cl];
        unsigned w5 = ((const unsigned*)(hlp + (size_t)s5 * OUT_CH))[cl];
        unsigned w6 = ((const unsigned*)(hlp + (size_t)s6 * OUT_CH))[cl];
        unsigned w7 = ((const unsigned*)(hlp + (size_t)s7 * OUT_CH))[cl];
        a0 += ((bf_lo(w0) + bf_lo(w1)) + (bf_lo(w2) + bf_lo(w3))) +
              ((bf_lo(w4) + bf_lo(w5)) + (bf_lo(w6) + bf_lo(w7)));
        a1 += ((bf_hi(w0) + bf_hi(w1)) + (bf_hi(w2) + bf_hi(w3))) +
              ((bf_hi(w4) + bf_hi(w5)) + (bf_hi(w6) + bf_hi(w7)));
    }
    for (; t + 4 <= cnt; t += 4) {
        int s0 = esrc[j0 + t],     s1 = esrc[j0 + t + 1];
        int s2 = esrc[j0 + t + 2], s3 = esrc[j0 + t + 3];
        unsigned w0 = ((const unsigned*)(hlp + (size_t)s0 * OUT_CH))[cl];
        unsigned w1 = ((const unsigned*)(hlp + (size_t)s1 * OUT_CH))[cl];
        unsigned w2 = ((const unsigned*)(hlp + (size_t)s2 * OUT_CH))[cl];
        unsigned w3 = ((const unsigned*)(hlp + (size_t)s3 * OUT_CH))[cl];
        a0 += (bf_lo(w0) + bf_lo(w1)) + (bf_lo(w2) + bf_lo(w3));
        a1 += (bf_hi(w0) + bf_hi(w1)) + (bf_hi(w2) + bf_hi(w3));
    }
    for (; t < cnt; ++t) {
        int s = esrc[j0 + t];
        unsigned w = ((const unsigned*)(hlp + (size_t)s * OUT_CH))[cl];
        a0 += bf_lo(w);
        a1 += bf_hi(w);
    }
    unsigned ws = ((const unsigned*)(hlp + (size_t)d * OUT_CH))[cl];  // self-loop
    float dd = dinv[d];
    float v0 = dd * (a0 + bf_lo(ws)) + b[2 * cl];
    float v1 = dd * (a1 + bf_hi(ws)) + b[2 * cl + 1];
    ((float2*)(out + (size_t)d * OUT_CH))[cl] = make_float2(v0, v1);
}

extern "C" void kernel_launch(void* const* d_in, const int* in_sizes, int n_in,
                              void* d_out, int out_size, void* d_ws, size_t ws_size,
                              hipStream_t stream) {
    const float* x  = (const float*)d_in[0];
    const int* ei   = (const int*)d_in[1];   // int32 from harness
    const float* W1 = (const float*)d_in[2];
    const float* b1 = (const float*)d_in[3];
    const float* W2 = (const float*)d_in[4];
    const float* b2 = (const float*)d_in[5];
    float* out = (float*)d_out;

    const int n = in_sizes[0] / IN_CH;      // 100000
    const int E = in_sizes[1] / 2;          // 1600000
    const int nb = (n + G_SZ - 1) >> G_SH;  // 782 buckets
    const int nchunk = (E + CHUNK - 1) / CHUNK;

    // workspace (ints): rowptr n | counts n | bcursor 1024 | packed nb*CAP |
    //   dinv n | xlp 32n (bf16 64/node; hlp bf16 16/node aliases) | hout 64n
    //   total ~= 52.7 MB
    int* rowptr  = (int*)d_ws;
    int* counts  = rowptr + n;
    int* bcursor = counts + n;
    int* packed  = bcursor + 1024;
    float* dinv  = (float*)(packed + (size_t)nb * CAP);
    __hip_bfloat16* xlp = (__hip_bfloat16*)(dinv + n);   // n*64 bf16
    __hip_bfloat16* hlp = xlp;                            // alias: xlp dead after k_agg1
    float* hout  = (float*)(xlp + (size_t)n * HID);       // n*64 f32

    // CSR build: fixed-cap regions -> coarse bucket -> fine sort (+rowptr/counts/dinv)
    k_init_bcur<<<(nb + 255) / 256, 256, 0, stream>>>(bcursor, nb);
    k_bucket<<<nchunk, 256, 0, stream>>>(ei, bcursor, packed, E, nb);
    k_sortbkt<<<nb, 256, 0, stream>>>(bcursor, packed, rowptr, counts, dinv, n);

    // layer 1
    k_gemm1<<<(n + 31) / 32, 256, 0, stream>>>(x, W1, dinv, xlp, n);
    k_agg1<<<(n + 7) / 8, 256, 0, stream>>>(rowptr, counts, packed, dinv, xlp, b1, hout, n);

    // layer 2
    k_gemm2<<<(n + 15) / 16, 256, 0, stream>>>(hout, W2, dinv, hlp, n);
    k_agg2<<<(n + 31) / 32, 256, 0, stream>>>(rowptr, counts, packed, dinv, hlp, b2, out, n);
}

// Round 11
// 131.691 us; speedup vs baseline: 2.8854x; 1.2854x over previous
//
#include <hip/hip_runtime.h>
#include <hip/hip_bf16.h>

#define IN_CH 128
#define HID 64
#define OUT_CH 16

#define G_SH 7
#define G_SZ 128          // dst nodes per bucket
#define NBK_MAX 800       // max buckets (n <= 102400)
#define CHUNK 4096        // edges per bucketing block
#define CAP 4096          // fixed capacity per bucket (mean 2048, sigma ~45)

#define XROW 136          // padded LDS row length in bf16 (128 + 8)

typedef short bf16x8 __attribute__((ext_vector_type(8)));
typedef float f32x4 __attribute__((ext_vector_type(4)));

__device__ __forceinline__ float bf_lo(unsigned w) { return __uint_as_float(w << 16); }
__device__ __forceinline__ float bf_hi(unsigned w) { return __uint_as_float(w & 0xffff0000u); }

__device__ __forceinline__ unsigned short f2bf(float f) {
    __hip_bfloat16 h = __float2bfloat16(f);
    unsigned short u;
    __builtin_memcpy(&u, &h, 2);
    return u;
}

__device__ __forceinline__ unsigned pack_bf2(float lo, float hi) {
    return ((unsigned)f2bf(hi) << 16) | (unsigned)f2bf(lo);
}

// ---------------- bucket cursors ----------------

__global__ void k_init_bcur(int* __restrict__ p, int nb) {
    int i = blockIdx.x * blockDim.x + threadIdx.x;
    if (i < nb) p[i] = i * CAP;
}

// ---------------- W1 -> bf16 transposed: wt[ch][k] ----------------

__global__ void k_cvtW(const float* __restrict__ W, unsigned short* __restrict__ wt) {
    int i = blockIdx.x * blockDim.x + threadIdx.x;
    if (i < IN_CH * HID) {
        int ch = i >> 7, k = i & 127;
        wt[ch * IN_CH + k] = f2bf(W[k * HID + ch]);
    }
}

// ---------------- edge bucketing (coarse sort by dst>>7) ----------------
// packed word: (d_local << 17) | src   (src < 2^17)
__global__ __launch_bounds__(256) void k_bucket(const int* __restrict__ ei,
                                                int* __restrict__ bcursor,
                                                int* __restrict__ packed, int E, int nb) {
    __shared__ int hcnt[NBK_MAX];
    __shared__ int hoff[NBK_MAX];
    __shared__ int hbase[NBK_MAX];
    __shared__ int hcur[NBK_MAX];
    __shared__ int stage[CHUNK];
    __shared__ unsigned short sbk[CHUNK];
    __shared__ int scan_s[256];
    __shared__ int sh_carry;

    int tid = threadIdx.x;
    int base = blockIdx.x * CHUNK;
    int cnt = E - base;
    if (cnt > CHUNK) cnt = CHUNK;
    for (int t = tid; t < nb; t += 256) { hcnt[t] = 0; hcur[t] = 0; }
    if (tid == 0) sh_carry = 0;
    __syncthreads();

    int mp[CHUNK / 256], mb[CHUNK / 256];
#pragma unroll
    for (int k = 0; k < CHUNK / 256; ++k) {
        int idx = base + k * 256 + tid;
        int p = 0, b = -1;
        if (idx < E) {
            int s = ei[idx];
            int d = ei[E + idx];
            b = d >> G_SH;
            p = ((d & (G_SZ - 1)) << 17) | s;
            atomicAdd(&hcnt[b], 1);
        }
        mp[k] = p; mb[k] = b;
    }
    __syncthreads();

    // exclusive scan of hcnt -> hoff
    for (int s0 = 0; s0 < nb; s0 += 256) {
        int i = s0 + tid;
        int v = (i < nb) ? hcnt[i] : 0;
        scan_s[tid] = v;
        __syncthreads();
        for (int off = 1; off < 256; off <<= 1) {
            int t = (tid >= off) ? scan_s[tid - off] : 0;
            __syncthreads();
            scan_s[tid] += t;
            __syncthreads();
        }
        if (i < nb) hoff[i] = sh_carry + scan_s[tid] - v;
        __syncthreads();
        if (tid == 255) sh_carry += scan_s[255];
        __syncthreads();
    }

    // reserve space in fixed-capacity bucket regions
    for (int t = tid; t < nb; t += 256)
        if (hcnt[t] > 0) hbase[t] = atomicAdd(&bcursor[t], hcnt[t]);
    __syncthreads();

    // LDS scatter into bucket-ordered staging
#pragma unroll
    for (int k = 0; k < CHUNK / 256; ++k) {
        int b = mb[k];
        if (b >= 0) {
            int slot = hoff[b] + atomicAdd(&hcur[b], 1);
            stage[slot] = mp[k];
            sbk[slot] = (unsigned short)b;
        }
    }
    __syncthreads();

    // coalesced run write-out
    for (int i = tid; i < cnt; i += 256) {
        int b = sbk[i];
        packed[hbase[b] + (i - hoff[b])] = stage[i];
    }
}

// ---- per-bucket fine counting sort; emits rowptr/counts/dinv per node ----

__global__ __launch_bounds__(256) void k_sortbkt(const int* __restrict__ bcursor,
                                                 int* __restrict__ packed,
                                                 int* __restrict__ rowptr,
                                                 int* __restrict__ counts,
                                                 float* __restrict__ dinv, int n) {
    __shared__ int sc[G_SZ];
    __shared__ int lcur[G_SZ];
    __shared__ int stage[CAP];
    __shared__ int sorted_[CAP];

    int tid = threadIdx.x;
    int bkt = blockIdx.x;
    int d0 = bkt << G_SH;
    int base = bkt * CAP;
    int L = bcursor[bkt] - base;

    if (tid < G_SZ) sc[tid] = 0;
    __syncthreads();
    // load + histogram in one pass
    for (int i = tid; i < L; i += 256) {
        int p = packed[base + i];
        stage[i] = p;
        atomicAdd(&sc[p >> 17], 1);
    }
    __syncthreads();
    int v = (tid < G_SZ) ? sc[tid] : 0;
    // inclusive Hillis-Steele over 128
    for (int off = 1; off < G_SZ; off <<= 1) {
        int t = (tid < G_SZ && tid >= off) ? sc[tid - off] : 0;
        __syncthreads();
        if (tid < G_SZ) sc[tid] += t;
        __syncthreads();
    }
    if (tid < G_SZ) {
        int excl = sc[tid] - v;
        lcur[tid] = excl;
        int d = d0 + tid;
        if (d < n) {
            rowptr[d] = base + excl;
            counts[d] = v;
            dinv[d] = rsqrtf((float)(v + 1));  // +1 = self-loop
        }
    }
    __syncthreads();
    for (int i = tid; i < L; i += 256) {
        int p = stage[i];
        int pos = atomicAdd(&lcur[p >> 17], 1);
        sorted_[pos] = p & 0x1FFFF;
    }
    __syncthreads();
    for (int i = tid; i < L; i += 256) packed[base + i] = sorted_[i];
}

// ---------------- layer 1: MFMA GEMM ----------------

// xlp = bf16(dinv * (x @ W1)); 64 nodes/block, 4 waves; 16x16x32 bf16 MFMA.
// A-frag: row = lane&15, k = (lane>>4)*8 + j (contiguous 8)   [m92 ladder layout]
// C/D:    col = lane&15, row = (lane>>4)*4 + reg              [m89]
__global__ __launch_bounds__(256) void k_gemm1(const float* __restrict__ x,
                                               const unsigned short* __restrict__ wt,
                                               const float* __restrict__ dinv,
                                               __hip_bfloat16* __restrict__ xlp, int n) {
    __shared__ unsigned short sx[64 * XROW];  // 17 KB, x tile in bf16 (padded rows)
    __shared__ unsigned short sw[64 * XROW];  // 17 KB, W^T in bf16 (padded rows)
    int tid = threadIdx.x;
    int node0 = blockIdx.x * 64;

    // stage W^T: 64 rows x 128 bf16, 8-short chunks
    for (int i = tid; i < 64 * 16; i += 256) {
        int row = i >> 4, kk = i & 15;
        uint4 v = ((const uint4*)wt)[i];  // source contiguous: row*128 + kk*8 shorts
        *(uint4*)&sw[row * XROW + kk * 8] = v;
    }
    // stage x: 64 rows x 128 fp32 -> bf16
    for (int i = tid; i < 64 * 32; i += 256) {
        int row = i >> 5, k4 = i & 31;
        int node = node0 + row;
        float4 v = (node < n) ? ((const float4*)(x + (size_t)node * IN_CH))[k4]
                              : make_float4(0.f, 0.f, 0.f, 0.f);
        uint2 p;
        p.x = pack_bf2(v.x, v.y);
        p.y = pack_bf2(v.z, v.w);
        *(uint2*)&sx[row * XROW + k4 * 4] = p;
    }
    __syncthreads();

    int w = tid >> 6, lane = tid & 63;
    int lrow = lane & 15, lg = lane >> 4;
    f32x4 acc0 = {0.f, 0.f, 0.f, 0.f}, acc1 = {0.f, 0.f, 0.f, 0.f};
    f32x4 acc2 = {0.f, 0.f, 0.f, 0.f}, acc3 = {0.f, 0.f, 0.f, 0.f};
    const unsigned short* ax = &sx[(16 * w + lrow) * XROW + lg * 8];
#pragma unroll
    for (int k0 = 0; k0 < IN_CH; k0 += 32) {
        bf16x8 a = *(const bf16x8*)&ax[k0];
        bf16x8 b0 = *(const bf16x8*)&sw[(lrow) * XROW + lg * 8 + k0];
        bf16x8 b1 = *(const bf16x8*)&sw[(16 + lrow) * XROW + lg * 8 + k0];
        bf16x8 b2 = *(const bf16x8*)&sw[(32 + lrow) * XROW + lg * 8 + k0];
        bf16x8 b3 = *(const bf16x8*)&sw[(48 + lrow) * XROW + lg * 8 + k0];
        acc0 = __builtin_amdgcn_mfma_f32_16x16x32_bf16(a, b0, acc0, 0, 0, 0);
        acc1 = __builtin_amdgcn_mfma_f32_16x16x32_bf16(a, b1, acc1, 0, 0, 0);
        acc2 = __builtin_amdgcn_mfma_f32_16x16x32_bf16(a, b2, acc2, 0, 0, 0);
        acc3 = __builtin_amdgcn_mfma_f32_16x16x32_bf16(a, b3, acc3, 0, 0, 0);
    }
    // epilogue: node = node0 + 16w + lg*4 + r ; ch = 16c + lrow
#pragma unroll
    for (int r = 0; r < 4; ++r) {
        int node = node0 + 16 * w + lg * 4 + r;
        if (node < n) {
            float dd = dinv[node];
            __hip_bfloat16* o = xlp + (size_t)node * HID + lrow;
            o[0]  = __float2bfloat16(dd * acc0[r]);
            o[16] = __float2bfloat16(dd * acc1[r]);
            o[32] = __float2bfloat16(dd * acc2[r]);
            o[48] = __float2bfloat16(dd * acc3[r]);
        }
    }
}

// hout[d] = relu(dd*(sum_s xlp[s] + xlp[d]) + b1), bf16 gathers.
// One 32-lane group per dst (cl = channel pair); 8-deep edge unroll.
__global__ __launch_bounds__(256) void k_agg1(const int* __restrict__ rowptr,
                                              const int* __restrict__ counts,
                                              const int* __restrict__ esrc,
                                              const float* __restrict__ dinv,
                                              const __hip_bfloat16* __restrict__ xlp,
                                              const float* __restrict__ b,
                                              float* __restrict__ hout, int n) {
    int d = blockIdx.x * 8 + (threadIdx.x >> 5);
    if (d >= n) return;
    int cl = threadIdx.x & 31;  // uint index -> channels {2cl, 2cl+1}
    int j0 = rowptr[d];
    int cnt = counts[d];
    float a0 = 0.f, a1 = 0.f;
    int t = 0;
    for (; t + 8 <= cnt; t += 8) {
        int s0 = esrc[j0 + t],     s1 = esrc[j0 + t + 1];
        int s2 = esrc[j0 + t + 2], s3 = esrc[j0 + t + 3];
        int s4 = esrc[j0 + t + 4], s5 = esrc[j0 + t + 5];
        int s6 = esrc[j0 + t + 6], s7 = esrc[j0 + t + 7];
        unsigned w0 = ((const unsigned*)(xlp + (size_t)s0 * HID))[cl];
        unsigned w1 = ((const unsigned*)(xlp + (size_t)s1 * HID))[cl];
        unsigned w2 = ((const unsigned*)(xlp + (size_t)s2 * HID))[cl];
        unsigned w3 = ((const unsigned*)(xlp + (size_t)s3 * HID))[cl];
        unsigned w4 = ((const unsigned*)(xlp + (size_t)s4 * HID))[cl];
        unsigned w5 = ((const unsigned*)(xlp + (size_t)s5 * HID))[cl];
        unsigned w6 = ((const unsigned*)(xlp + (size_t)s6 * HID))[cl];
        unsigned w7 = ((const unsigned*)(xlp + (size_t)s7 * HID))[cl];
        a0 += ((bf_lo(w0) + bf_lo(w1)) + (bf_lo(w2) + bf_lo(w3))) +
              ((bf_lo(w4) + bf_lo(w5)) + (bf_lo(w6) + bf_lo(w7)));
        a1 += ((bf_hi(w0) + bf_hi(w1)) + (bf_hi(w2) + bf_hi(w3))) +
              ((bf_hi(w4) + bf_hi(w5)) + (bf_hi(w6) + bf_hi(w7)));
    }
    for (; t + 4 <= cnt; t += 4) {
        int s0 = esrc[j0 + t],     s1 = esrc[j0 + t + 1];
        int s2 = esrc[j0 + t + 2], s3 = esrc[j0 + t + 3];
        unsigned w0 = ((const unsigned*)(xlp + (size_t)s0 * HID))[cl];
        unsigned w1 = ((const unsigned*)(xlp + (size_t)s1 * HID))[cl];
        unsigned w2 = ((const unsigned*)(xlp + (size_t)s2 * HID))[cl];
        unsigned w3 = ((const unsigned*)(xlp + (size_t)s3 * HID))[cl];
        a0 += (bf_lo(w0) + bf_lo(w1)) + (bf_lo(w2) + bf_lo(w3));
        a1 += (bf_hi(w0) + bf_hi(w1)) + (bf_hi(w2) + bf_hi(w3));
    }
    for (; t < cnt; ++t) {
        int s = esrc[j0 + t];
        unsigned w = ((const unsigned*)(xlp + (size_t)s * HID))[cl];
        a0 += bf_lo(w);
        a1 += bf_hi(w);
    }
    unsigned ws = ((const unsigned*)(xlp + (size_t)d * HID))[cl];  // self-loop
    float dd = dinv[d];
    float v0 = dd * (a0 + bf_lo(ws)) + b[2 * cl];
    float v1 = dd * (a1 + bf_hi(ws)) + b[2 * cl + 1];
    ((float2*)(hout + (size_t)d * HID))[cl] = make_float2(fmaxf(v0, 0.f), fmaxf(v1, 0.f));
}

// ---------------- layer 2 ----------------

// hlp = bf16(dinv * (h @ W2)); 16 nodes/block
__global__ __launch_bounds__(256) void k_gemm2(const float* __restrict__ h,
                                               const float* __restrict__ W,
                                               const float* __restrict__ dinv,
                                               __hip_bfloat16* __restrict__ hlp, int n) {
    __shared__ float sW[HID * OUT_CH];
    __shared__ float sh[16][HID];
    int tid = threadIdx.x;
    for (int t = tid; t < HID * OUT_CH; t += 256) sW[t] = W[t];
    int node0 = blockIdx.x * 16;
    for (int t = tid; t < 16 * HID / 4; t += 256) {
        int r = t >> 4, k4 = t & 15;
        int node = node0 + r;
        float4 v = (node < n) ? ((const float4*)(h + (size_t)node * HID))[k4]
                              : make_float4(0.f, 0.f, 0.f, 0.f);
        ((float4*)sh[r])[k4] = v;
    }
    __syncthreads();
    int r = tid >> 4, j = tid & 15;
    int node = node0 + r;
    if (node >= n) return;
    float acc = 0.f;
#pragma unroll
    for (int k = 0; k < HID; ++k)
        acc += sh[r][k] * sW[k * OUT_CH + j];
    hlp[(size_t)node * OUT_CH + j] = __float2bfloat16(dinv[node] * acc);
}

// out[d] = dd*(sum_s hlp[s] + hlp[d]) + b2, bf16 gathers from 3.2 MB table.
// One 8-lane group per dst; 8-deep unroll.
__global__ __launch_bounds__(256) void k_agg2(const int* __restrict__ rowptr,
                                              const int* __restrict__ counts,
                                              const int* __restrict__ esrc,
                                              const float* __restrict__ dinv,
                                              const __hip_bfloat16* __restrict__ hlp,
                                              const float* __restrict__ b,
                                              float* __restrict__ out, int n) {
    int d = blockIdx.x * 32 + (threadIdx.x >> 3);
    if (d >= n) return;
    int cl = threadIdx.x & 7;  // uint index -> channels {2cl, 2cl+1}
    int j0 = rowptr[d];
    int cnt = counts[d];
    float a0 = 0.f, a1 = 0.f;
    int t = 0;
    for (; t + 8 <= cnt; t += 8) {
        int s0 = esrc[j0 + t],     s1 = esrc[j0 + t + 1];
        int s2 = esrc[j0 + t + 2], s3 = esrc[j0 + t + 3];
        int s4 = esrc[j0 + t + 4], s5 = esrc[j0 + t + 5];
        int s6 = esrc[j0 + t + 6], s7 = esrc[j0 + t + 7];
        unsigned w0 = ((const unsigned*)(hlp + (size_t)s0 * OUT_CH))[cl];
        unsigned w1 = ((const unsigned*)(hlp + (size_t)s1 * OUT_CH))[cl];
        unsigned w2 = ((const unsigned*)(hlp + (size_t)s2 * OUT_CH))[cl];
        unsigned w3 = ((const unsigned*)(hlp + (size_t)s3 * OUT_CH))[cl];
        unsigned w4 = ((const unsigned*)(hlp + (size_t)s4 * OUT_CH))[cl];
        unsigned w5 = ((const unsigned*)(hlp + (size_t)s5 * OUT_CH))[cl];
        unsigned w6 = ((const unsigned*)(hlp + (size_t)s6 * OUT_CH))[cl];
        unsigned w7 = ((const unsigned*)(hlp + (size_t)s7 * OUT_CH))[cl];
        a0 += ((bf_lo(w0) + bf_lo(w1)) + (bf_lo(w2) + bf_lo(w3))) +
              ((bf_lo(w4) + bf_lo(w5)) + (bf_lo(w6) + bf_lo(w7)));
        a1 += ((bf_hi(w0) + bf_hi(w1)) + (bf_hi(w2) + bf_hi(w3))) +
              ((bf_hi(w4) + bf_hi(w5)) + (bf_hi(w6) + bf_hi(w7)));
    }
    for (; t + 4 <= cnt; t += 4) {
        int s0 = esrc[j0 + t],     s1 = esrc[j0 + t + 1];
        int s2 = esrc[j0 + t + 2], s3 = esrc[j0 + t + 3];
        unsigned w0 = ((const unsigned*)(hlp + (size_t)s0 * OUT_CH))[cl];
        unsigned w1 = ((const unsigned*)(hlp + (size_t)s1 * OUT_CH))[cl];
        unsigned w2 = ((const unsigned*)(hlp + (size_t)s2 * OUT_CH))[cl];
        unsigned w3 = ((const unsigned*)(hlp + (size_t)s3 * OUT_CH))[cl];
        a0 += (bf_lo(w0) + bf_lo(w1)) + (bf_lo(w2) + bf_lo(w3));
        a1 += (bf_hi(w0) + bf_hi(w1)) + (bf_hi(w2) + bf_hi(w3));
    }
    for (; t < cnt; ++t) {
        int s = esrc[j0 + t];
        unsigned w = ((const unsigned*)(hlp + (size_t)s * OUT_CH))[cl];
        a0 += bf_lo(w);
        a1 += bf_hi(w);
    }
    unsigned ws = ((const unsigned*)(hlp + (size_t)d * OUT_CH))[cl];  // self-loop
    float dd = dinv[d];
    float v0 = dd * (a0 + bf_lo(ws)) + b[2 * cl];
    float v1 = dd * (a1 + bf_hi(ws)) + b[2 * cl + 1];
    ((float2*)(out + (size_t)d * OUT_CH))[cl] = make_float2(v0, v1);
}

extern "C" void kernel_launch(void* const* d_in, const int* in_sizes, int n_in,
                              void* d_out, int out_size, void* d_ws, size_t ws_size,
                              hipStream_t stream) {
    const float* x  = (const float*)d_in[0];
    const int* ei   = (const int*)d_in[1];   // int32 from harness
    const float* W1 = (const float*)d_in[2];
    const float* b1 = (const float*)d_in[3];
    const float* W2 = (const float*)d_in[4];
    const float* b2 = (const float*)d_in[5];
    float* out = (float*)d_out;

    const int n = in_sizes[0] / IN_CH;      // 100000
    const int E = in_sizes[1] / 2;          // 1600000
    const int nb = (n + G_SZ - 1) >> G_SH;  // 782 buckets
    const int nchunk = (E + CHUNK - 1) / CHUNK;

    // workspace (ints): rowptr n | counts n | bcursor 1024 | wtbf 4096 | packed nb*CAP |
    //   dinv n | xlp 32n (bf16 64/node; hlp bf16 16/node aliases) | hout 64n
    //   total ~= 52.7 MB
    int* rowptr  = (int*)d_ws;
    int* counts  = rowptr + n;
    int* bcursor = counts + n;
    unsigned short* wtbf = (unsigned short*)(bcursor + 1024);  // 8192 shorts (4096 ints)
    int* packed  = (int*)(wtbf + 8192);
    float* dinv  = (float*)(packed + (size_t)nb * CAP);
    __hip_bfloat16* xlp = (__hip_bfloat16*)(dinv + n);   // n*64 bf16
    __hip_bfloat16* hlp = xlp;                            // alias: xlp dead after k_agg1
    float* hout  = (float*)(xlp + (size_t)n * HID);       // n*64 f32

    // CSR build + W conversion
    k_init_bcur<<<(nb + 255) / 256, 256, 0, stream>>>(bcursor, nb);
    k_cvtW<<<(IN_CH * HID + 255) / 256, 256, 0, stream>>>(W1, wtbf);
    k_bucket<<<nchunk, 256, 0, stream>>>(ei, bcursor, packed, E, nb);
    k_sortbkt<<<nb, 256, 0, stream>>>(bcursor, packed, rowptr, counts, dinv, n);

    // layer 1
    k_gemm1<<<(n + 63) / 64, 256, 0, stream>>>(x, wtbf, dinv, xlp, n);
    k_agg1<<<(n + 7) / 8, 256, 0, stream>>>(rowptr, counts, packed, dinv, xlp, b1, hout, n);

    // layer 2
    k_gemm2<<<(n + 15) / 16, 256, 0, stream>>>(hout, W2, dinv, hlp, n);
    k_agg2<<<(n + 31) / 32, 256, 0, stream>>>(rowptr, counts, packed, dinv, hlp, b2, out, n);
}

// Round 13
// 128.217 us; speedup vs baseline: 2.9636x; 1.0271x over previous
//
#include <hip/hip_runtime.h>
#include <hip/hip_bf16.h>

#define IN_CH 128
#define HID 64
#define OUT_CH 16

#define G_SH 7
#define G_SZ 128          // dst nodes per bucket
#define NBK_MAX 800       // max buckets (n <= 102400)
#define CHUNK 4096        // edges per bucketing block
#define CAP 4096          // fixed capacity per bucket (mean 2048, sigma ~45)

#define XROW 136          // padded LDS row length in bf16 (128 + 8)

typedef short bf16x8 __attribute__((ext_vector_type(8)));
typedef float f32x4 __attribute__((ext_vector_type(4)));

__device__ __forceinline__ float bf_lo(unsigned w) { return __uint_as_float(w << 16); }
__device__ __forceinline__ float bf_hi(unsigned w) { return __uint_as_float(w & 0xffff0000u); }

__device__ __forceinline__ unsigned short f2bf(float f) {
    __hip_bfloat16 h = __float2bfloat16(f);
    unsigned short u;
    __builtin_memcpy(&u, &h, 2);
    return u;
}

__device__ __forceinline__ unsigned pack_bf2(float lo, float hi) {
    return ((unsigned)f2bf(hi) << 16) | (unsigned)f2bf(lo);
}

// ---------------- bucket cursors ----------------

__global__ void k_init_bcur(int* __restrict__ p, int nb) {
    int i = blockIdx.x * blockDim.x + threadIdx.x;
    if (i < nb) p[i] = i * CAP;
}

// ---------------- W1 -> bf16 transposed: wt[ch][k] ----------------

__global__ void k_cvtW(const float* __restrict__ W, unsigned short* __restrict__ wt) {
    int i = blockIdx.x * blockDim.x + threadIdx.x;
    if (i < IN_CH * HID) {
        int ch = i >> 7, k = i & 127;
        wt[ch * IN_CH + k] = f2bf(W[k * HID + ch]);
    }
}

// ---------------- edge bucketing (coarse sort by dst>>7) ----------------
// ROUND-11 VERBATIM (known good). packed word: (d_local << 17) | src
__global__ __launch_bounds__(256) void k_bucket(const int* __restrict__ ei,
                                                int* __restrict__ bcursor,
                                                int* __restrict__ packed, int E, int nb) {
    __shared__ int hcnt[NBK_MAX];
    __shared__ int hoff[NBK_MAX];
    __shared__ int hbase[NBK_MAX];
    __shared__ int hcur[NBK_MAX];
    __shared__ int stage[CHUNK];
    __shared__ unsigned short sbk[CHUNK];
    __shared__ int scan_s[256];
    __shared__ int sh_carry;

    int tid = threadIdx.x;
    int base = blockIdx.x * CHUNK;
    int cnt = E - base;
    if (cnt > CHUNK) cnt = CHUNK;
    for (int t = tid; t < nb; t += 256) { hcnt[t] = 0; hcur[t] = 0; }
    if (tid == 0) sh_carry = 0;
    __syncthreads();

    int mp[CHUNK / 256], mb[CHUNK / 256];
#pragma unroll
    for (int k = 0; k < CHUNK / 256; ++k) {
        int idx = base + k * 256 + tid;
        int p = 0, b = -1;
        if (idx < E) {
            int s = ei[idx];
            int d = ei[E + idx];
            b = d >> G_SH;
            p = ((d & (G_SZ - 1)) << 17) | s;
            atomicAdd(&hcnt[b], 1);
        }
        mp[k] = p; mb[k] = b;
    }
    __syncthreads();

    // exclusive scan of hcnt -> hoff
    for (int s0 = 0; s0 < nb; s0 += 256) {
        int i = s0 + tid;
        int v = (i < nb) ? hcnt[i] : 0;
        scan_s[tid] = v;
        __syncthreads();
        for (int off = 1; off < 256; off <<= 1) {
            int t = (tid >= off) ? scan_s[tid - off] : 0;
            __syncthreads();
            scan_s[tid] += t;
            __syncthreads();
        }
        if (i < nb) hoff[i] = sh_carry + scan_s[tid] - v;
        __syncthreads();
        if (tid == 255) sh_carry += scan_s[255];
        __syncthreads();
    }

    // reserve space in fixed-capacity bucket regions
    for (int t = tid; t < nb; t += 256)
        if (hcnt[t] > 0) hbase[t] = atomicAdd(&bcursor[t], hcnt[t]);
    __syncthreads();

    // LDS scatter into bucket-ordered staging
#pragma unroll
    for (int k = 0; k < CHUNK / 256; ++k) {
        int b = mb[k];
        if (b >= 0) {
            int slot = hoff[b] + atomicAdd(&hcur[b], 1);
            stage[slot] = mp[k];
            sbk[slot] = (unsigned short)b;
        }
    }
    __syncthreads();

    // coalesced run write-out
    for (int i = tid; i < cnt; i += 256) {
        int b = sbk[i];
        packed[hbase[b] + (i - hoff[b])] = stage[i];
    }
}

// ---- per-bucket fine counting sort; emits rowptr/counts/dinv per node ----

__global__ __launch_bounds__(256) void k_sortbkt(const int* __restrict__ bcursor,
                                                 int* __restrict__ packed,
                                                 int* __restrict__ rowptr,
                                                 int* __restrict__ counts,
                                                 float* __restrict__ dinv, int n) {
    __shared__ int sc[G_SZ];
    __shared__ int lcur[G_SZ];
    __shared__ int stage[CAP];
    __shared__ int sorted_[CAP];

    int tid = threadIdx.x;
    int bkt = blockIdx.x;
    int d0 = bkt << G_SH;
    int base = bkt * CAP;
    int L = bcursor[bkt] - base;

    if (tid < G_SZ) sc[tid] = 0;
    __syncthreads();
    for (int i = tid; i < L; i += 256) {
        int p = packed[base + i];
        stage[i] = p;
        atomicAdd(&sc[p >> 17], 1);
    }
    __syncthreads();
    int v = (tid < G_SZ) ? sc[tid] : 0;
    for (int off = 1; off < G_SZ; off <<= 1) {
        int t = (tid < G_SZ && tid >= off) ? sc[tid - off] : 0;
        __syncthreads();
        if (tid < G_SZ) sc[tid] += t;
        __syncthreads();
    }
    if (tid < G_SZ) {
        int excl = sc[tid] - v;
        lcur[tid] = excl;
        int d = d0 + tid;
        if (d < n) {
            rowptr[d] = base + excl;
            counts[d] = v;
            dinv[d] = rsqrtf((float)(v + 1));  // +1 = self-loop
        }
    }
    __syncthreads();
    for (int i = tid; i < L; i += 256) {
        int p = stage[i];
        int pos = atomicAdd(&lcur[p >> 17], 1);
        sorted_[pos] = p & 0x1FFFF;
    }
    __syncthreads();
    for (int i = tid; i < L; i += 256) packed[base + i] = sorted_[i];
}

// ---------------- layer 1: MFMA GEMM ----------------

__global__ __launch_bounds__(256) void k_gemm1(const float* __restrict__ x,
                                               const unsigned short* __restrict__ wt,
                                               const float* __restrict__ dinv,
                                               __hip_bfloat16* __restrict__ xlp, int n) {
    __shared__ unsigned short sx[64 * XROW];
    __shared__ unsigned short sw[64 * XROW];
    int tid = threadIdx.x;
    int node0 = blockIdx.x * 64;

    for (int i = tid; i < 64 * 16; i += 256) {
        int row = i >> 4, kk = i & 15;
        uint4 v = ((const uint4*)wt)[i];
        *(uint4*)&sw[row * XROW + kk * 8] = v;
    }
    for (int i = tid; i < 64 * 32; i += 256) {
        int row = i >> 5, k4 = i & 31;
        int node = node0 + row;
        float4 v = (node < n) ? ((const float4*)(x + (size_t)node * IN_CH))[k4]
                              : make_float4(0.f, 0.f, 0.f, 0.f);
        uint2 p;
        p.x = pack_bf2(v.x, v.y);
        p.y = pack_bf2(v.z, v.w);
        *(uint2*)&sx[row * XROW + k4 * 4] = p;
    }
    __syncthreads();

    int w = tid >> 6, lane = tid & 63;
    int lrow = lane & 15, lg = lane >> 4;
    f32x4 acc0 = {0.f, 0.f, 0.f, 0.f}, acc1 = {0.f, 0.f, 0.f, 0.f};
    f32x4 acc2 = {0.f, 0.f, 0.f, 0.f}, acc3 = {0.f, 0.f, 0.f, 0.f};
    const unsigned short* ax = &sx[(16 * w + lrow) * XROW + lg * 8];
#pragma unroll
    for (int k0 = 0; k0 < IN_CH; k0 += 32) {
        bf16x8 a = *(const bf16x8*)&ax[k0];
        bf16x8 b0 = *(const bf16x8*)&sw[(lrow) * XROW + lg * 8 + k0];
        bf16x8 b1 = *(const bf16x8*)&sw[(16 + lrow) * XROW + lg * 8 + k0];
        bf16x8 b2 = *(const bf16x8*)&sw[(32 + lrow) * XROW + lg * 8 + k0];
        bf16x8 b3 = *(const bf16x8*)&sw[(48 + lrow) * XROW + lg * 8 + k0];
        acc0 = __builtin_amdgcn_mfma_f32_16x16x32_bf16(a, b0, acc0, 0, 0, 0);
        acc1 = __builtin_amdgcn_mfma_f32_16x16x32_bf16(a, b1, acc1, 0, 0, 0);
        acc2 = __builtin_amdgcn_mfma_f32_16x16x32_bf16(a, b2, acc2, 0, 0, 0);
        acc3 = __builtin_amdgcn_mfma_f32_16x16x32_bf16(a, b3, acc3, 0, 0, 0);
    }
#pragma unroll
    for (int r = 0; r < 4; ++r) {
        int node = node0 + 16 * w + lg * 4 + r;
        if (node < n) {
            float dd = dinv[node];
            __hip_bfloat16* o = xlp + (size_t)node * HID + lrow;
            o[0]  = __float2bfloat16(dd * acc0[r]);
            o[16] = __float2bfloat16(dd * acc1[r]);
            o[32] = __float2bfloat16(dd * acc2[r]);
            o[48] = __float2bfloat16(dd * acc3[r]);
        }
    }
}

// ---------------- fused agg1 + gemm2 (hardened: barriers, no early return) ----

__global__ __launch_bounds__(256) void k_agg1f(const int* __restrict__ rowptr,
                                               const int* __restrict__ counts,
                                               const int* __restrict__ esrc,
                                               const float* __restrict__ dinv,
                                               const __hip_bfloat16* __restrict__ xlp,
                                               const float* __restrict__ b1,
                                               const float* __restrict__ W2,
                                               __hip_bfloat16* __restrict__ hlp, int n) {
    __shared__ float sW2[HID * OUT_CH];  // 4 KB
    __shared__ float sh[8][HID];         // 2 KB
    int tid = threadIdx.x;
    for (int i = tid; i < HID * OUT_CH; i += 256) sW2[i] = W2[i];
    __syncthreads();

    int g = tid >> 5;
    int cl = tid & 31;  // uint index -> channels {2cl, 2cl+1}
    int d = blockIdx.x * 8 + g;
    bool active = (d < n);
    int j0 = 0, cnt = 0;
    float dd = 0.f;
    if (active) { j0 = rowptr[d]; cnt = counts[d]; dd = dinv[d]; }

    float a0 = 0.f, a1 = 0.f;
    int t = 0;
    for (; t + 8 <= cnt; t += 8) {
        int s0 = esrc[j0 + t],     s1 = esrc[j0 + t + 1];
        int s2 = esrc[j0 + t + 2], s3 = esrc[j0 + t + 3];
        int s4 = esrc[j0 + t + 4], s5 = esrc[j0 + t + 5];
        int s6 = esrc[j0 + t + 6], s7 = esrc[j0 + t + 7];
        unsigned w0 = ((const unsigned*)(xlp + (size_t)s0 * HID))[cl];
        unsigned w1 = ((const unsigned*)(xlp + (size_t)s1 * HID))[cl];
        unsigned w2 = ((const unsigned*)(xlp + (size_t)s2 * HID))[cl];
        unsigned w3 = ((const unsigned*)(xlp + (size_t)s3 * HID))[cl];
        unsigned w4 = ((const unsigned*)(xlp + (size_t)s4 * HID))[cl];
        unsigned w5 = ((const unsigned*)(xlp + (size_t)s5 * HID))[cl];
        unsigned w6 = ((const unsigned*)(xlp + (size_t)s6 * HID))[cl];
        unsigned w7 = ((const unsigned*)(xlp + (size_t)s7 * HID))[cl];
        a0 += ((bf_lo(w0) + bf_lo(w1)) + (bf_lo(w2) + bf_lo(w3))) +
              ((bf_lo(w4) + bf_lo(w5)) + (bf_lo(w6) + bf_lo(w7)));
        a1 += ((bf_hi(w0) + bf_hi(w1)) + (bf_hi(w2) + bf_hi(w3))) +
              ((bf_hi(w4) + bf_hi(w5)) + (bf_hi(w6) + bf_hi(w7)));
    }
    for (; t + 4 <= cnt; t += 4) {
        int s0 = esrc[j0 + t],     s1 = esrc[j0 + t + 1];
        int s2 = esrc[j0 + t + 2], s3 = esrc[j0 + t + 3];
        unsigned w0 = ((const unsigned*)(xlp + (size_t)s0 * HID))[cl];
        unsigned w1 = ((const unsigned*)(xlp + (size_t)s1 * HID))[cl];
        unsigned w2 = ((const unsigned*)(xlp + (size_t)s2 * HID))[cl];
        unsigned w3 = ((const unsigned*)(xlp + (size_t)s3 * HID))[cl];
        a0 += (bf_lo(w0) + bf_lo(w1)) + (bf_lo(w2) + bf_lo(w3));
        a1 += (bf_hi(w0) + bf_hi(w1)) + (bf_hi(w2) + bf_hi(w3));
    }
    for (; t < cnt; ++t) {
        int s = esrc[j0 + t];
        unsigned w = ((const unsigned*)(xlp + (size_t)s * HID))[cl];
        a0 += bf_lo(w);
        a1 += bf_hi(w);
    }

    if (active) {
        unsigned ws = ((const unsigned*)(xlp + (size_t)d * HID))[cl];  // self-loop
        float v0 = fmaxf(dd * (a0 + bf_lo(ws)) + b1[2 * cl], 0.f);
        float v1 = fmaxf(dd * (a1 + bf_hi(ws)) + b1[2 * cl + 1], 0.f);
        ((float2*)sh[g])[cl] = make_float2(v0, v1);  // sh[g][2cl..2cl+1] = h[d]
    }
    __syncthreads();  // hard ordering: staging visible before matvec reads

    if (active) {
        int j = cl & 15, kh = cl >> 4;
        float acc = 0.f;
#pragma unroll 8
        for (int k = 0; k < 32; ++k) {
            int kk = kh * 32 + k;
            acc += sh[g][kk] * sW2[kk * OUT_CH + j];
        }
        acc += __shfl_xor(acc, 16);  // combine k-halves
        if (cl < 16)
            hlp[(size_t)d * OUT_CH + j] = __float2bfloat16(dd * acc);
    }
}

// ---------------- layer 2 aggregation ----------------

__global__ __launch_bounds__(256) void k_agg2(const int* __restrict__ rowptr,
                                              const int* __restrict__ counts,
                                              const int* __restrict__ esrc,
                                              const float* __restrict__ dinv,
                                              const __hip_bfloat16* __restrict__ hlp,
                                              const float* __restrict__ b,
                                              float* __restrict__ out, int n) {
    int d = blockIdx.x * 32 + (threadIdx.x >> 3);
    if (d >= n) return;
    int cl = threadIdx.x & 7;
    int j0 = rowptr[d];
    int cnt = counts[d];
    float a0 = 0.f, a1 = 0.f;
    int t = 0;
    for (; t + 8 <= cnt; t += 8) {
        int s0 = esrc[j0 + t],     s1 = esrc[j0 + t + 1];
        int s2 = esrc[j0 + t + 2], s3 = esrc[j0 + t + 3];
        int s4 = esrc[j0 + t + 4], s5 = esrc[j0 + t + 5];
        int s6 = esrc[j0 + t + 6], s7 = esrc[j0 + t + 7];
        unsigned w0 = ((const unsigned*)(hlp + (size_t)s0 * OUT_CH))[cl];
        unsigned w1 = ((const unsigned*)(hlp + (size_t)s1 * OUT_CH))[cl];
        unsigned w2 = ((const unsigned*)(hlp + (size_t)s2 * OUT_CH))[cl];
        unsigned w3 = ((const unsigned*)(hlp + (size_t)s3 * OUT_CH))[cl];
        unsigned w4 = ((const unsigned*)(hlp + (size_t)s4 * OUT_CH))[cl];
        unsigned w5 = ((const unsigned*)(hlp + (size_t)s5 * OUT_CH))[cl];
        unsigned w6 = ((const unsigned*)(hlp + (size_t)s6 * OUT_CH))[cl];
        unsigned w7 = ((const unsigned*)(hlp + (size_t)s7 * OUT_CH))[cl];
        a0 += ((bf_lo(w0) + bf_lo(w1)) + (bf_lo(w2) + bf_lo(w3))) +
              ((bf_lo(w4) + bf_lo(w5)) + (bf_lo(w6) + bf_lo(w7)));
        a1 += ((bf_hi(w0) + bf_hi(w1)) + (bf_hi(w2) + bf_hi(w3))) +
              ((bf_hi(w4) + bf_hi(w5)) + (bf_hi(w6) + bf_hi(w7)));
    }
    for (; t + 4 <= cnt; t += 4) {
        int s0 = esrc[j0 + t],     s1 = esrc[j0 + t + 1];
        int s2 = esrc[j0 + t + 2], s3 = esrc[j0 + t + 3];
        unsigned w0 = ((const unsigned*)(hlp + (size_t)s0 * OUT_CH))[cl];
        unsigned w1 = ((const unsigned*)(hlp + (size_t)s1 * OUT_CH))[cl];
        unsigned w2 = ((const unsigned*)(hlp + (size_t)s2 * OUT_CH))[cl];
        unsigned w3 = ((const unsigned*)(hlp + (size_t)s3 * OUT_CH))[cl];
        a0 += (bf_lo(w0) + bf_lo(w1)) + (bf_lo(w2) + bf_lo(w3));
        a1 += (bf_hi(w0) + bf_hi(w1)) + (bf_hi(w2) + bf_hi(w3));
    }
    for (; t < cnt; ++t) {
        int s = esrc[j0 + t];
        unsigned w = ((const unsigned*)(hlp + (size_t)s * OUT_CH))[cl];
        a0 += bf_lo(w);
        a1 += bf_hi(w);
    }
    unsigned ws = ((const unsigned*)(hlp + (size_t)d * OUT_CH))[cl];  // self-loop
    float dd = dinv[d];
    float v0 = dd * (a0 + bf_lo(ws)) + b[2 * cl];
    float v1 = dd * (a1 + bf_hi(ws)) + b[2 * cl + 1];
    ((float2*)(out + (size_t)d * OUT_CH))[cl] = make_float2(v0, v1);
}

extern "C" void kernel_launch(void* const* d_in, const int* in_sizes, int n_in,
                              void* d_out, int out_size, void* d_ws, size_t ws_size,
                              hipStream_t stream) {
    const float* x  = (const float*)d_in[0];
    const int* ei   = (const int*)d_in[1];   // int32 from harness
    const float* W1 = (const float*)d_in[2];
    const float* b1 = (const float*)d_in[3];
    const float* W2 = (const float*)d_in[4];
    const float* b2 = (const float*)d_in[5];
    float* out = (float*)d_out;

    const int n = in_sizes[0] / IN_CH;      // 100000
    const int E = in_sizes[1] / 2;          // 1600000
    const int nb = (n + G_SZ - 1) >> G_SH;  // 782 buckets
    const int nchunk = (E + CHUNK - 1) / CHUNK;

    int* rowptr  = (int*)d_ws;
    int* counts  = rowptr + n;
    int* bcursor = counts + n;
    unsigned short* wtbf = (unsigned short*)(bcursor + 1024);  // 8192 shorts
    int* packed  = (int*)(wtbf + 8192);
    float* dinv  = (float*)(packed + (size_t)nb * CAP);
    __hip_bfloat16* xlp = (__hip_bfloat16*)(dinv + n);          // n*64 bf16
    __hip_bfloat16* hlp = xlp + (size_t)n * HID;                // n*16 bf16 (separate)

    // CSR build + W conversion (round-11 verbatim k_bucket)
    k_init_bcur<<<(nb + 255) / 256, 256, 0, stream>>>(bcursor, nb);
    k_cvtW<<<(IN_CH * HID + 255) / 256, 256, 0, stream>>>(W1, wtbf);
    k_bucket<<<nchunk, 256, 0, stream>>>(ei, bcursor, packed, E, nb);
    k_sortbkt<<<nb, 256, 0, stream>>>(bcursor, packed, rowptr, counts, dinv, n);

    // layer 1 (+ fused layer-2 transform)
    k_gemm1<<<(n + 63) / 64, 256, 0, stream>>>(x, wtbf, dinv, xlp, n);
    k_agg1f<<<(n + 7) / 8, 256, 0, stream>>>(rowptr, counts, packed, dinv, xlp, b1, W2, hlp, n);

    // layer 2 aggregation
    k_agg2<<<(n + 31) / 32, 256, 0, stream>>>(rowptr, counts, packed, dinv, hlp, b2, out, n);
}

// Round 14
// 122.756 us; speedup vs baseline: 3.0955x; 1.0445x over previous
//
#include <hip/hip_runtime.h>
#include <hip/hip_bf16.h>

#define IN_CH 128
#define HID 64
#define OUT_CH 16

#define G_SH 7
#define G_SZ 128          // dst nodes per bucket
#define NBK_MAX 800       // max buckets (n <= 102400)
#define CHUNK 4096        // edges per bucketing block
#define CAP 4096          // fixed capacity per bucket (mean 2048, sigma ~45)

#define XROW 136          // padded LDS row length in bf16 (128 + 8)

typedef short bf16x8 __attribute__((ext_vector_type(8)));
typedef float f32x4 __attribute__((ext_vector_type(4)));

__device__ __forceinline__ float bf_lo(unsigned w) { return __uint_as_float(w << 16); }
__device__ __forceinline__ float bf_hi(unsigned w) { return __uint_as_float(w & 0xffff0000u); }

__device__ __forceinline__ unsigned short f2bf(float f) {
    __hip_bfloat16 h = __float2bfloat16(f);
    unsigned short u;
    __builtin_memcpy(&u, &h, 2);
    return u;
}

__device__ __forceinline__ unsigned pack_bf2(float lo, float hi) {
    return ((unsigned)f2bf(hi) << 16) | (unsigned)f2bf(lo);
}

// ---------------- setup: bucket cursors + W1->bf16 transposed ----------------

__global__ void k_setup(int* __restrict__ bcur, int nb,
                        const float* __restrict__ W, unsigned short* __restrict__ wt) {
    int i = blockIdx.x * blockDim.x + threadIdx.x;
    if (i < nb) bcur[i] = i * CAP;
    if (i < IN_CH * HID) {
        int ch = i >> 7, k = i & 127;
        wt[ch * IN_CH + k] = f2bf(W[k * HID + ch]);
    }
}

// ---------------- edge bucketing (coarse sort by dst>>7) ----------------
// ROUND-11 VERBATIM (known good, frozen). packed word: (d_local << 17) | src
__global__ __launch_bounds__(256) void k_bucket(const int* __restrict__ ei,
                                                int* __restrict__ bcursor,
                                                int* __restrict__ packed, int E, int nb) {
    __shared__ int hcnt[NBK_MAX];
    __shared__ int hoff[NBK_MAX];
    __shared__ int hbase[NBK_MAX];
    __shared__ int hcur[NBK_MAX];
    __shared__ int stage[CHUNK];
    __shared__ unsigned short sbk[CHUNK];
    __shared__ int scan_s[256];
    __shared__ int sh_carry;

    int tid = threadIdx.x;
    int base = blockIdx.x * CHUNK;
    int cnt = E - base;
    if (cnt > CHUNK) cnt = CHUNK;
    for (int t = tid; t < nb; t += 256) { hcnt[t] = 0; hcur[t] = 0; }
    if (tid == 0) sh_carry = 0;
    __syncthreads();

    int mp[CHUNK / 256], mb[CHUNK / 256];
#pragma unroll
    for (int k = 0; k < CHUNK / 256; ++k) {
        int idx = base + k * 256 + tid;
        int p = 0, b = -1;
        if (idx < E) {
            int s = ei[idx];
            int d = ei[E + idx];
            b = d >> G_SH;
            p = ((d & (G_SZ - 1)) << 17) | s;
            atomicAdd(&hcnt[b], 1);
        }
        mp[k] = p; mb[k] = b;
    }
    __syncthreads();

    // exclusive scan of hcnt -> hoff
    for (int s0 = 0; s0 < nb; s0 += 256) {
        int i = s0 + tid;
        int v = (i < nb) ? hcnt[i] : 0;
        scan_s[tid] = v;
        __syncthreads();
        for (int off = 1; off < 256; off <<= 1) {
            int t = (tid >= off) ? scan_s[tid - off] : 0;
            __syncthreads();
            scan_s[tid] += t;
            __syncthreads();
        }
        if (i < nb) hoff[i] = sh_carry + scan_s[tid] - v;
        __syncthreads();
        if (tid == 255) sh_carry += scan_s[255];
        __syncthreads();
    }

    // reserve space in fixed-capacity bucket regions
    for (int t = tid; t < nb; t += 256)
        if (hcnt[t] > 0) hbase[t] = atomicAdd(&bcursor[t], hcnt[t]);
    __syncthreads();

    // LDS scatter into bucket-ordered staging
#pragma unroll
    for (int k = 0; k < CHUNK / 256; ++k) {
        int b = mb[k];
        if (b >= 0) {
            int slot = hoff[b] + atomicAdd(&hcur[b], 1);
            stage[slot] = mp[k];
            sbk[slot] = (unsigned short)b;
        }
    }
    __syncthreads();

    // coalesced run write-out
    for (int i = tid; i < cnt; i += 256) {
        int b = sbk[i];
        packed[hbase[b] + (i - hoff[b])] = stage[i];
    }
}

// ---- per-bucket fine counting sort; emits rowptr/counts/dinv per node ----

__global__ __launch_bounds__(256) void k_sortbkt(const int* __restrict__ bcursor,
                                                 int* __restrict__ packed,
                                                 int* __restrict__ rowptr,
                                                 int* __restrict__ counts,
                                                 float* __restrict__ dinv, int n) {
    __shared__ int sc[G_SZ];
    __shared__ int lcur[G_SZ];
    __shared__ int stage[CAP];
    __shared__ int sorted_[CAP];

    int tid = threadIdx.x;
    int bkt = blockIdx.x;
    int d0 = bkt << G_SH;
    int base = bkt * CAP;
    int L = bcursor[bkt] - base;

    if (tid < G_SZ) sc[tid] = 0;
    __syncthreads();
    for (int i = tid; i < L; i += 256) {
        int p = packed[base + i];
        stage[i] = p;
        atomicAdd(&sc[p >> 17], 1);
    }
    __syncthreads();
    int v = (tid < G_SZ) ? sc[tid] : 0;
    for (int off = 1; off < G_SZ; off <<= 1) {
        int t = (tid < G_SZ && tid >= off) ? sc[tid - off] : 0;
        __syncthreads();
        if (tid < G_SZ) sc[tid] += t;
        __syncthreads();
    }
    if (tid < G_SZ) {
        int excl = sc[tid] - v;
        lcur[tid] = excl;
        int d = d0 + tid;
        if (d < n) {
            rowptr[d] = base + excl;
            counts[d] = v;
            dinv[d] = rsqrtf((float)(v + 1));  // +1 = self-loop
        }
    }
    __syncthreads();
    for (int i = tid; i < L; i += 256) {
        int p = stage[i];
        int pos = atomicAdd(&lcur[p >> 17], 1);
        sorted_[pos] = p & 0x1FFFF;
    }
    __syncthreads();
    for (int i = tid; i < L; i += 256) packed[base + i] = sorted_[i];
}

// ---------------- layer 1: MFMA GEMM ----------------

__global__ __launch_bounds__(256) void k_gemm1(const float* __restrict__ x,
                                               const unsigned short* __restrict__ wt,
                                               const float* __restrict__ dinv,
                                               __hip_bfloat16* __restrict__ xlp, int n) {
    __shared__ unsigned short sx[64 * XROW];
    __shared__ unsigned short sw[64 * XROW];
    int tid = threadIdx.x;
    int node0 = blockIdx.x * 64;

    for (int i = tid; i < 64 * 16; i += 256) {
        int row = i >> 4, kk = i & 15;
        uint4 v = ((const uint4*)wt)[i];
        *(uint4*)&sw[row * XROW + kk * 8] = v;
    }
    for (int i = tid; i < 64 * 32; i += 256) {
        int row = i >> 5, k4 = i & 31;
        int node = node0 + row;
        float4 v = (node < n) ? ((const float4*)(x + (size_t)node * IN_CH))[k4]
                              : make_float4(0.f, 0.f, 0.f, 0.f);
        uint2 p;
        p.x = pack_bf2(v.x, v.y);
        p.y = pack_bf2(v.z, v.w);
        *(uint2*)&sx[row * XROW + k4 * 4] = p;
    }
    __syncthreads();

    int w = tid >> 6, lane = tid & 63;
    int lrow = lane & 15, lg = lane >> 4;
    f32x4 acc0 = {0.f, 0.f, 0.f, 0.f}, acc1 = {0.f, 0.f, 0.f, 0.f};
    f32x4 acc2 = {0.f, 0.f, 0.f, 0.f}, acc3 = {0.f, 0.f, 0.f, 0.f};
    const unsigned short* ax = &sx[(16 * w + lrow) * XROW + lg * 8];
#pragma unroll
    for (int k0 = 0; k0 < IN_CH; k0 += 32) {
        bf16x8 a = *(const bf16x8*)&ax[k0];
        bf16x8 b0 = *(const bf16x8*)&sw[(lrow) * XROW + lg * 8 + k0];
        bf16x8 b1 = *(const bf16x8*)&sw[(16 + lrow) * XROW + lg * 8 + k0];
        bf16x8 b2 = *(const bf16x8*)&sw[(32 + lrow) * XROW + lg * 8 + k0];
        bf16x8 b3 = *(const bf16x8*)&sw[(48 + lrow) * XROW + lg * 8 + k0];
        acc0 = __builtin_amdgcn_mfma_f32_16x16x32_bf16(a, b0, acc0, 0, 0, 0);
        acc1 = __builtin_amdgcn_mfma_f32_16x16x32_bf16(a, b1, acc1, 0, 0, 0);
        acc2 = __builtin_amdgcn_mfma_f32_16x16x32_bf16(a, b2, acc2, 0, 0, 0);
        acc3 = __builtin_amdgcn_mfma_f32_16x16x32_bf16(a, b3, acc3, 0, 0, 0);
    }
#pragma unroll
    for (int r = 0; r < 4; ++r) {
        int node = node0 + 16 * w + lg * 4 + r;
        if (node < n) {
            float dd = dinv[node];
            __hip_bfloat16* o = xlp + (size_t)node * HID + lrow;
            o[0]  = __float2bfloat16(dd * acc0[r]);
            o[16] = __float2bfloat16(dd * acc1[r]);
            o[32] = __float2bfloat16(dd * acc2[r]);
            o[48] = __float2bfloat16(dd * acc3[r]);
        }
    }
}

// ---------------- fused agg1 + gemm2 (no mid barrier: same-wave LDS only) ----

__global__ __launch_bounds__(256) void k_agg1f(const int* __restrict__ rowptr,
                                               const int* __restrict__ counts,
                                               const int* __restrict__ esrc,
                                               const float* __restrict__ dinv,
                                               const __hip_bfloat16* __restrict__ xlp,
                                               const float* __restrict__ b1,
                                               const float* __restrict__ W2,
                                               __hip_bfloat16* __restrict__ hlp, int n) {
    __shared__ float sW2[HID * OUT_CH];  // 4 KB
    __shared__ float sh[8][HID];         // 2 KB
    int tid = threadIdx.x;
    for (int i = tid; i < HID * OUT_CH; i += 256) sW2[i] = W2[i];
    __syncthreads();  // sW2 visible to all waves

    int g = tid >> 5;
    int cl = tid & 31;  // uint index -> channels {2cl, 2cl+1}
    int d = blockIdx.x * 8 + g;
    if (d >= n) return;  // n % 8 == 0 in practice; safe (after the only barrier)
    int j0 = rowptr[d];
    int cnt = counts[d];
    float dd = dinv[d];

    float a0 = 0.f, a1 = 0.f;
    int t = 0;
    for (; t + 8 <= cnt; t += 8) {
        int s0 = esrc[j0 + t],     s1 = esrc[j0 + t + 1];
        int s2 = esrc[j0 + t + 2], s3 = esrc[j0 + t + 3];
        int s4 = esrc[j0 + t + 4], s5 = esrc[j0 + t + 5];
        int s6 = esrc[j0 + t + 6], s7 = esrc[j0 + t + 7];
        unsigned w0 = ((const unsigned*)(xlp + (size_t)s0 * HID))[cl];
        unsigned w1 = ((const unsigned*)(xlp + (size_t)s1 * HID))[cl];
        unsigned w2 = ((const unsigned*)(xlp + (size_t)s2 * HID))[cl];
        unsigned w3 = ((const unsigned*)(xlp + (size_t)s3 * HID))[cl];
        unsigned w4 = ((const unsigned*)(xlp + (size_t)s4 * HID))[cl];
        unsigned w5 = ((const unsigned*)(xlp + (size_t)s5 * HID))[cl];
        unsigned w6 = ((const unsigned*)(xlp + (size_t)s6 * HID))[cl];
        unsigned w7 = ((const unsigned*)(xlp + (size_t)s7 * HID))[cl];
        a0 += ((bf_lo(w0) + bf_lo(w1)) + (bf_lo(w2) + bf_lo(w3))) +
              ((bf_lo(w4) + bf_lo(w5)) + (bf_lo(w6) + bf_lo(w7)));
        a1 += ((bf_hi(w0) + bf_hi(w1)) + (bf_hi(w2) + bf_hi(w3))) +
              ((bf_hi(w4) + bf_hi(w5)) + (bf_hi(w6) + bf_hi(w7)));
    }
    for (; t + 4 <= cnt; t += 4) {
        int s0 = esrc[j0 + t],     s1 = esrc[j0 + t + 1];
        int s2 = esrc[j0 + t + 2], s3 = esrc[j0 + t + 3];
        unsigned w0 = ((const unsigned*)(xlp + (size_t)s0 * HID))[cl];
        unsigned w1 = ((const unsigned*)(xlp + (size_t)s1 * HID))[cl];
        unsigned w2 = ((const unsigned*)(xlp + (size_t)s2 * HID))[cl];
        unsigned w3 = ((const unsigned*)(xlp + (size_t)s3 * HID))[cl];
        a0 += (bf_lo(w0) + bf_lo(w1)) + (bf_lo(w2) + bf_lo(w3));
        a1 += (bf_hi(w0) + bf_hi(w1)) + (bf_hi(w2) + bf_hi(w3));
    }
    for (; t < cnt; ++t) {
        int s = esrc[j0 + t];
        unsigned w = ((const unsigned*)(xlp + (size_t)s * HID))[cl];
        a0 += bf_lo(w);
        a1 += bf_hi(w);
    }

    unsigned ws = ((const unsigned*)(xlp + (size_t)d * HID))[cl];  // self-loop
    float v0 = fmaxf(dd * (a0 + bf_lo(ws)) + b1[2 * cl], 0.f);
    float v1 = fmaxf(dd * (a1 + bf_hi(ws)) + b1[2 * cl + 1], 0.f);
    // group-private staging: written and read by the SAME 32 lanes (one wave half);
    // whole wave executes the write (both groups) before any lane's read — SIMD order.
    ((float2*)sh[g])[cl] = make_float2(v0, v1);

    int j = cl & 15, kh = cl >> 4;
    float acc = 0.f;
#pragma unroll 8
    for (int k = 0; k < 32; ++k) {
        int kk = kh * 32 + k;
        acc += sh[g][kk] * sW2[kk * OUT_CH + j];
    }
    acc += __shfl_xor(acc, 16);  // combine k-halves
    if (cl < 16)
        hlp[(size_t)d * OUT_CH + j] = __float2bfloat16(dd * acc);
}

// ---------------- layer 2 aggregation ----------------

__global__ __launch_bounds__(256) void k_agg2(const int* __restrict__ rowptr,
                                              const int* __restrict__ counts,
                                              const int* __restrict__ esrc,
                                              const float* __restrict__ dinv,
                                              const __hip_bfloat16* __restrict__ hlp,
                                              const float* __restrict__ b,
                                              float* __restrict__ out, int n) {
    int d = blockIdx.x * 32 + (threadIdx.x >> 3);
    if (d >= n) return;
    int cl = threadIdx.x & 7;
    int j0 = rowptr[d];
    int cnt = counts[d];
    float a0 = 0.f, a1 = 0.f;
    int t = 0;
    for (; t + 8 <= cnt; t += 8) {
        int s0 = esrc[j0 + t],     s1 = esrc[j0 + t + 1];
        int s2 = esrc[j0 + t + 2], s3 = esrc[j0 + t + 3];
        int s4 = esrc[j0 + t + 4], s5 = esrc[j0 + t + 5];
        int s6 = esrc[j0 + t + 6], s7 = esrc[j0 + t + 7];
        unsigned w0 = ((const unsigned*)(hlp + (size_t)s0 * OUT_CH))[cl];
        unsigned w1 = ((const unsigned*)(hlp + (size_t)s1 * OUT_CH))[cl];
        unsigned w2 = ((const unsigned*)(hlp + (size_t)s2 * OUT_CH))[cl];
        unsigned w3 = ((const unsigned*)(hlp + (size_t)s3 * OUT_CH))[cl];
        unsigned w4 = ((const unsigned*)(hlp + (size_t)s4 * OUT_CH))[cl];
        unsigned w5 = ((const unsigned*)(hlp + (size_t)s5 * OUT_CH))[cl];
        unsigned w6 = ((const unsigned*)(hlp + (size_t)s6 * OUT_CH))[cl];
        unsigned w7 = ((const unsigned*)(hlp + (size_t)s7 * OUT_CH))[cl];
        a0 += ((bf_lo(w0) + bf_lo(w1)) + (bf_lo(w2) + bf_lo(w3))) +
              ((bf_lo(w4) + bf_lo(w5)) + (bf_lo(w6) + bf_lo(w7)));
        a1 += ((bf_hi(w0) + bf_hi(w1)) + (bf_hi(w2) + bf_hi(w3))) +
              ((bf_hi(w4) + bf_hi(w5)) + (bf_hi(w6) + bf_hi(w7)));
    }
    for (; t + 4 <= cnt; t += 4) {
        int s0 = esrc[j0 + t],     s1 = esrc[j0 + t + 1];
        int s2 = esrc[j0 + t + 2], s3 = esrc[j0 + t + 3];
        unsigned w0 = ((const unsigned*)(hlp + (size_t)s0 * OUT_CH))[cl];
        unsigned w1 = ((const unsigned*)(hlp + (size_t)s1 * OUT_CH))[cl];
        unsigned w2 = ((const unsigned*)(hlp + (size_t)s2 * OUT_CH))[cl];
        unsigned w3 = ((const unsigned*)(hlp + (size_t)s3 * OUT_CH))[cl];
        a0 += (bf_lo(w0) + bf_lo(w1)) + (bf_lo(w2) + bf_lo(w3));
        a1 += (bf_hi(w0) + bf_hi(w1)) + (bf_hi(w2) + bf_hi(w3));
    }
    for (; t < cnt; ++t) {
        int s = esrc[j0 + t];
        unsigned w = ((const unsigned*)(hlp + (size_t)s * OUT_CH))[cl];
        a0 += bf_lo(w);
        a1 += bf_hi(w);
    }
    unsigned ws = ((const unsigned*)(hlp + (size_t)d * OUT_CH))[cl];  // self-loop
    float dd = dinv[d];
    float v0 = dd * (a0 + bf_lo(ws)) + b[2 * cl];
    float v1 = dd * (a1 + bf_hi(ws)) + b[2 * cl + 1];
    ((float2*)(out + (size_t)d * OUT_CH))[cl] = make_float2(v0, v1);
}

extern "C" void kernel_launch(void* const* d_in, const int* in_sizes, int n_in,
                              void* d_out, int out_size, void* d_ws, size_t ws_size,
                              hipStream_t stream) {
    const float* x  = (const float*)d_in[0];
    const int* ei   = (const int*)d_in[1];   // int32 from harness
    const float* W1 = (const float*)d_in[2];
    const float* b1 = (const float*)d_in[3];
    const float* W2 = (const float*)d_in[4];
    const float* b2 = (const float*)d_in[5];
    float* out = (float*)d_out;

    const int n = in_sizes[0] / IN_CH;      // 100000
    const int E = in_sizes[1] / 2;          // 1600000
    const int nb = (n + G_SZ - 1) >> G_SH;  // 782 buckets
    const int nchunk = (E + CHUNK - 1) / CHUNK;

    int* rowptr  = (int*)d_ws;
    int* counts  = rowptr + n;
    int* bcursor = counts + n;
    unsigned short* wtbf = (unsigned short*)(bcursor + 1024);  // 8192 shorts
    int* packed  = (int*)(wtbf + 8192);
    float* dinv  = (float*)(packed + (size_t)nb * CAP);
    __hip_bfloat16* xlp = (__hip_bfloat16*)(dinv + n);          // n*64 bf16
    __hip_bfloat16* hlp = xlp + (size_t)n * HID;                // n*16 bf16 (separate)

    // setup + CSR build (k_bucket frozen at round-11 version)
    k_setup<<<(IN_CH * HID + 255) / 256, 256, 0, stream>>>(bcursor, nb, W1, wtbf);
    k_bucket<<<nchunk, 256, 0, stream>>>(ei, bcursor, packed, E, nb);
    k_sortbkt<<<nb, 256, 0, stream>>>(bcursor, packed, rowptr, counts, dinv, n);

    // layer 1 (+ fused layer-2 transform)
    k_gemm1<<<(n + 63) / 64, 256, 0, stream>>>(x, wtbf, dinv, xlp, n);
    k_agg1f<<<(n + 7) / 8, 256, 0, stream>>>(rowptr, counts, packed, dinv, xlp, b1, W2, hlp, n);

    // layer 2 aggregation
    k_agg2<<<(n + 31) / 32, 256, 0, stream>>>(rowptr, counts, packed, dinv, hlp, b2, out, n);
}